// Round 5
// baseline (128.297 us; speedup 1.0000x reference)
//
#include <hip/hip_runtime.h>
#include <math.h>

#define HD 256
#define SEQ 4096
#define NR 16384
#define NHEADS 4
#define EPSV 1e-5f

typedef __attribute__((ext_vector_type(8))) short bf16x8;
typedef __attribute__((ext_vector_type(4))) float f32x4;

__device__ inline short f2bf(float f) {
    unsigned u = __float_as_uint(f);
    u += 0x7FFF + ((u >> 16) & 1);     // round-to-nearest-even
    return (short)(u >> 16);
}
__device__ inline float bf2f(short s) {
    return __uint_as_float(((unsigned)(unsigned short)s) << 16);
}

// ---------------------------------------------------------------------------
// Prep: transpose+cast weights to bf16 (tasks 0-3) and cast x -> bf16 (task 4)
// ---------------------------------------------------------------------------
__global__ __launch_bounds__(256) void prep_kernel(
    const float* __restrict__ Wc, const float* __restrict__ Wa,
    const float* __restrict__ Wg, const float* __restrict__ Wp,
    const float* __restrict__ x,
    short* __restrict__ WcT, short* __restrict__ WaT,
    short* __restrict__ WgT, short* __restrict__ WpT,
    short* __restrict__ xb)
{
    int task = blockIdx.y;
    int idx = blockIdx.x * 256 + threadIdx.x;
    if (task == 4) {                       // x cast: NR*HD/4 = 1048576 jobs
        float4 v = ((const float4*)x)[idx];
        short4 o;
        o.x = f2bf(v.x); o.y = f2bf(v.y); o.z = f2bf(v.z); o.w = f2bf(v.w);
        ((short4*)xb)[idx] = o;
        return;
    }
    const float* W; short* Wt; int K;
    if (task == 0)      { W = Wc; Wt = WcT; K = 256; }
    else if (task == 1) { W = Wa; Wt = WaT; K = 256; }
    else if (task == 2) { W = Wg; Wt = WgT; K = 512; }
    else                { W = Wp; Wt = WpT; K = 256; }
    if (idx >= K * 256) return;
    int n = idx & 255, k = idx >> 8;
    Wt[n * K + k] = f2bf(W[idx]);
}

// ---------------------------------------------------------------------------
// MFMA GEMM (bf16): C_bf16 = A @ B (BT = B^T).
// Block tile 64x64 = 2x2 waves of 32x32; grid 1024 blocks -> 16 waves/CU.
// ---------------------------------------------------------------------------
__global__ __launch_bounds__(256, 4) void gemm_bf(const short* __restrict__ A,
                                                  const short* __restrict__ BT,
                                                  short* __restrict__ C)
{
    int tid = threadIdx.x;
    int lane = tid & 63, wid = tid >> 6;
    int wm = wid >> 1, wn = wid & 1;
    int m0 = blockIdx.y * 64 + wm * 32;
    int n0 = blockIdx.x * 64 + wn * 32;
    int lm = lane & 15, lk = (lane >> 4) * 8;
    f32x4 acc[2][2] = {};
#pragma unroll
    for (int kk = 0; kk < HD; kk += 32) {
        bf16x8 a[2], b[2];
#pragma unroll
        for (int i = 0; i < 2; ++i)
            a[i] = *(const bf16x8*)(A + (size_t)(m0 + i * 16 + lm) * HD + kk + lk);
#pragma unroll
        for (int j = 0; j < 2; ++j)
            b[j] = *(const bf16x8*)(BT + (size_t)(n0 + j * 16 + lm) * HD + kk + lk);
#pragma unroll
        for (int i = 0; i < 2; ++i)
#pragma unroll
            for (int j = 0; j < 2; ++j)
                acc[i][j] = __builtin_amdgcn_mfma_f32_16x16x32_bf16(a[i], b[j], acc[i][j], 0, 0, 0);
    }
    int rbase = (lane >> 4) * 4;
#pragma unroll
    for (int i = 0; i < 2; ++i)
#pragma unroll
        for (int j = 0; j < 2; ++j)
#pragma unroll
            for (int r = 0; r < 4; ++r)
                C[(size_t)(m0 + i * 16 + rbase + r) * HD + n0 + j * 16 + lm] = f2bf(acc[i][j][r]);
}

// ---------------------------------------------------------------------------
// GEMM2 + fused es/et dots. Block's 64-col slice = exactly one head
// (head = blockIdx.x). Per-wave partial dots (32 cols) combined via LDS.
// ---------------------------------------------------------------------------
__global__ __launch_bounds__(256, 4) void gemm_dots(const short* __restrict__ A,
                                                    const short* __restrict__ BT,
                                                    const float* __restrict__ a_src,
                                                    const float* __restrict__ a_tgt,
                                                    short* __restrict__ C,
                                                    float* __restrict__ es,
                                                    float* __restrict__ et)
{
    __shared__ float esp[2][64], etp[2][64];
    int tid = threadIdx.x;
    int lane = tid & 63, wid = tid >> 6;
    int wm = wid >> 1, wn = wid & 1;
    int m0 = blockIdx.y * 64 + wm * 32;
    int n0 = blockIdx.x * 64 + wn * 32;
    int lm = lane & 15, lk = (lane >> 4) * 8;
    f32x4 acc[2][2] = {};
#pragma unroll
    for (int kk = 0; kk < HD; kk += 32) {
        bf16x8 a[2], b[2];
#pragma unroll
        for (int i = 0; i < 2; ++i)
            a[i] = *(const bf16x8*)(A + (size_t)(m0 + i * 16 + lm) * HD + kk + lk);
#pragma unroll
        for (int j = 0; j < 2; ++j)
            b[j] = *(const bf16x8*)(BT + (size_t)(n0 + j * 16 + lm) * HD + kk + lk);
#pragma unroll
        for (int i = 0; i < 2; ++i)
#pragma unroll
            for (int j = 0; j < 2; ++j)
                acc[i][j] = __builtin_amdgcn_mfma_f32_16x16x32_bf16(a[i], b[j], acc[i][j], 0, 0, 0);
    }
    int rbase = (lane >> 4) * 4;
#pragma unroll
    for (int i = 0; i < 2; ++i)
#pragma unroll
        for (int j = 0; j < 2; ++j)
#pragma unroll
            for (int r = 0; r < 4; ++r)
                C[(size_t)(m0 + i * 16 + rbase + r) * HD + n0 + j * 16 + lm] = f2bf(acc[i][j][r]);

    // fused per-head dots (fp32 accum precision)
    float as2[2], at2[2];
#pragma unroll
    for (int j = 0; j < 2; ++j) {
        as2[j] = a_src[n0 + j * 16 + lm];
        at2[j] = a_tgt[n0 + j * 16 + lm];
    }
#pragma unroll
    for (int i = 0; i < 2; ++i)
#pragma unroll
        for (int r = 0; r < 4; ++r) {
            float ps = acc[i][0][r] * as2[0] + acc[i][1][r] * as2[1];
            float pt = acc[i][0][r] * at2[0] + acc[i][1][r] * at2[1];
#pragma unroll
            for (int o = 1; o < 16; o <<= 1) {
                ps += __shfl_xor(ps, o, 64);
                pt += __shfl_xor(pt, o, 64);
            }
            if (lm == 0) {
                int rl = wm * 32 + i * 16 + rbase + r;
                esp[wn][rl] = ps;
                etp[wn][rl] = pt;
            }
        }
    __syncthreads();
    if (tid < 64) {
        int row = blockIdx.y * 64 + tid;
        int head = blockIdx.x;
        es[row * NHEADS + head] = esp[0][tid] + esp[1][tid];
        et[row * NHEADS + head] = etp[0][tid] + etp[1][tid];
    }
}

// ---------------------------------------------------------------------------
// Layer 0: 15-tap stencil over bf16 support + bias + residual + LN -> bf16.
// 1 wave = 1 row; lane owns 4 channels.
// ---------------------------------------------------------------------------
__global__ __launch_bounds__(256) void conv_ln(const short* __restrict__ sup,
                                               const float* __restrict__ x,
                                               const float* __restrict__ bc,
                                               const float* __restrict__ g,
                                               const float* __restrict__ bb,
                                               short* __restrict__ out)
{
    int wv = threadIdx.x >> 6, lane = threadIdx.x & 63;
    int t = blockIdx.x * 4 + wv;
    int p = t & (SEQ - 1);
    int c0 = lane * 4;
    float a0 = 0.f, a1 = 0.f, a2 = 0.f, a3 = 0.f;
#pragma unroll
    for (int i = 0; i < 15; ++i) {
        int d = (i < 7) ? (i - 7) : (i - 6);
        int qp = p + d;
        if (qp >= 0 && qp < SEQ) {
            short4 s4 = *(const short4*)(sup + (size_t)(t + d) * HD + c0);
            float wd = 1.f / (1.f + (float)((d < 0) ? -d : d));
            a0 += wd * bf2f(s4.x); a1 += wd * bf2f(s4.y);
            a2 += wd * bf2f(s4.z); a3 += wd * bf2f(s4.w);
        }
    }
    float4 xv  = *(const float4*)(x  + (size_t)t * HD + c0);
    float4 bcv = *(const float4*)(bc + c0);
    float v0 = a0 + bcv.x + xv.x, v1 = a1 + bcv.y + xv.y;
    float v2 = a2 + bcv.z + xv.z, v3 = a3 + bcv.w + xv.w;
    float s = v0 + v1 + v2 + v3;
    float q = v0 * v0 + v1 * v1 + v2 * v2 + v3 * v3;
#pragma unroll
    for (int o = 1; o < 64; o <<= 1) { s += __shfl_xor(s, o, 64); q += __shfl_xor(q, o, 64); }
    float mu = s * (1.f / HD);
    float var = q * (1.f / HD) - mu * mu;
    float inv = rsqrtf(var + EPSV);
    float4 gv = *(const float4*)(g + c0);
    float4 bv = *(const float4*)(bb + c0);
    short4 o4;
    o4.x = f2bf((v0 - mu) * inv * gv.x + bv.x);
    o4.y = f2bf((v1 - mu) * inv * gv.y + bv.y);
    o4.z = f2bf((v2 - mu) * inv * gv.z + bv.z);
    o4.w = f2bf((v3 - mu) * inv * gv.w + bv.w);
    *(short4*)(out + (size_t)t * HD + c0) = o4;
}

// ---------------------------------------------------------------------------
// Layer 1: inline per-head softmax + 15-tap aggregation + residual + LN.
// 1 wave = 1 row.
// ---------------------------------------------------------------------------
__global__ __launch_bounds__(256) void attn_ln(const short* __restrict__ hb,
                                               const float* __restrict__ es,
                                               const float* __restrict__ et,
                                               const float* __restrict__ x,
                                               const float* __restrict__ ba,
                                               const float* __restrict__ g,
                                               const float* __restrict__ bb,
                                               short* __restrict__ out)
{
    int wv = threadIdx.x >> 6, lane = threadIdx.x & 63;
    int t = blockIdx.x * 4 + wv;
    int p = t & (SEQ - 1);

    // --- inline softmax: 60 (tap,head) terms across lanes ---
    int tap = lane >> 2, hh = lane & 3;
    float lg = -1e30f, wd = 0.f;
    bool okk = false;
    if (tap < 15) {
        int d = (tap < 7) ? (tap - 7) : (tap - 6);
        int qp = p + d;
        okk = (qp >= 0) && (qp < SEQ);
        if (okk) {
            float l = es[(t + d) * NHEADS + hh] + et[t * NHEADS + hh];
            lg = (l > 0.f) ? l : 0.2f * l;
        }
        wd = 1.f / (1.f + (float)((d < 0) ? -d : d));
    }
    float m = lg;
#pragma unroll
    for (int o = 4; o < 64; o <<= 1) m = fmaxf(m, __shfl_xor(m, o, 64));
    float un = okk ? __expf(lg - m) * wd : 0.f;
    float den = un;
#pragma unroll
    for (int o = 4; o < 64; o <<= 1) den += __shfl_xor(den, o, 64);
    float alpha_l = un / (den + 1e-9f);

    // gather this lane's head's 15 alphas
    int hd = lane >> 4;
    float al[15];
#pragma unroll
    for (int i = 0; i < 15; ++i) al[i] = __shfl(alpha_l, i * 4 + hd, 64);

    // --- aggregation ---
    int c0 = lane * 4;
    float a0 = 0.f, a1 = 0.f, a2 = 0.f, a3 = 0.f;
#pragma unroll
    for (int i = 0; i < 15; ++i) {
        int d = (i < 7) ? (i - 7) : (i - 6);
        int qp = p + d;
        if (qp >= 0 && qp < SEQ) {
            short4 s4 = *(const short4*)(hb + (size_t)(t + d) * HD + c0);
            a0 += al[i] * bf2f(s4.x); a1 += al[i] * bf2f(s4.y);
            a2 += al[i] * bf2f(s4.z); a3 += al[i] * bf2f(s4.w);
        }
    }
    float4 xv  = *(const float4*)(x  + (size_t)t * HD + c0);
    float4 bav = *(const float4*)(ba + c0);
    float v0 = a0 + bav.x + xv.x, v1 = a1 + bav.y + xv.y;
    float v2 = a2 + bav.z + xv.z, v3 = a3 + bav.w + xv.w;
    float s = v0 + v1 + v2 + v3;
    float q = v0 * v0 + v1 * v1 + v2 * v2 + v3 * v3;
#pragma unroll
    for (int o = 1; o < 64; o <<= 1) { s += __shfl_xor(s, o, 64); q += __shfl_xor(q, o, 64); }
    float mu = s * (1.f / HD);
    float var = q * (1.f / HD) - mu * mu;
    float inv = rsqrtf(var + EPSV);
    float4 gv = *(const float4*)(g + c0);
    float4 bv = *(const float4*)(bb + c0);
    short4 o4;
    o4.x = f2bf((v0 - mu) * inv * gv.x + bv.x);
    o4.y = f2bf((v1 - mu) * inv * gv.y + bv.y);
    o4.z = f2bf((v2 - mu) * inv * gv.z + bv.z);
    o4.w = f2bf((v3 - mu) * inv * gv.w + bv.w);
    *(short4*)(out + (size_t)t * HD + c0) = o4;
}

// ---------------------------------------------------------------------------
// Final: gate = sigmoid(x@Wg_top + gs2@Wg_bot + bg); out = x + gate*(gs2@Wp+bp)
// Block tile 64x64 (2x2 waves of 32x32), grid 1024 blocks.
// ---------------------------------------------------------------------------
__global__ __launch_bounds__(256, 4) void final_mfma(const float* __restrict__ x,
                                                     const short* __restrict__ xb,
                                                     const short* __restrict__ gs2b,
                                                     const short* __restrict__ WgT,
                                                     const float* __restrict__ bg,
                                                     const short* __restrict__ WpT,
                                                     const float* __restrict__ bp,
                                                     float* __restrict__ out)
{
    int tid = threadIdx.x;
    int lane = tid & 63, wid = tid >> 6;
    int wm = wid >> 1, wn = wid & 1;
    int m0 = blockIdx.y * 64 + wm * 32;
    int n0 = blockIdx.x * 64 + wn * 32;
    int lm = lane & 15, lk = (lane >> 4) * 8;
    f32x4 accg[2][2] = {}, accp[2][2] = {};
#pragma unroll
    for (int kk = 0; kk < HD; kk += 32) {
        bf16x8 ax[2], ag[2], b1[2], b2[2], b3[2];
#pragma unroll
        for (int i = 0; i < 2; ++i) {
            size_t off = (size_t)(m0 + i * 16 + lm) * HD + kk + lk;
            ax[i] = *(const bf16x8*)(xb + off);
            ag[i] = *(const bf16x8*)(gs2b + off);
        }
#pragma unroll
        for (int j = 0; j < 2; ++j) {
            size_t n = (size_t)(n0 + j * 16 + lm);
            b1[j] = *(const bf16x8*)(WgT + n * 512 + kk + lk);
            b2[j] = *(const bf16x8*)(WgT + n * 512 + 256 + kk + lk);
            b3[j] = *(const bf16x8*)(WpT + n * 256 + kk + lk);
        }
#pragma unroll
        for (int i = 0; i < 2; ++i)
#pragma unroll
            for (int j = 0; j < 2; ++j) {
                accg[i][j] = __builtin_amdgcn_mfma_f32_16x16x32_bf16(ax[i], b1[j], accg[i][j], 0, 0, 0);
                accg[i][j] = __builtin_amdgcn_mfma_f32_16x16x32_bf16(ag[i], b2[j], accg[i][j], 0, 0, 0);
                accp[i][j] = __builtin_amdgcn_mfma_f32_16x16x32_bf16(ag[i], b3[j], accp[i][j], 0, 0, 0);
            }
    }
    int rbase = (lane >> 4) * 4;
#pragma unroll
    for (int i = 0; i < 2; ++i)
#pragma unroll
        for (int j = 0; j < 2; ++j)
#pragma unroll
            for (int r = 0; r < 4; ++r) {
                size_t m = (size_t)(m0 + i * 16 + rbase + r);
                int n = n0 + j * 16 + lm;
                float gate = 1.f / (1.f + __expf(-(accg[i][j][r] + bg[n])));
                float pv = accp[i][j][r] + bp[n];
                out[m * HD + n] = x[m * HD + n] + gate * pv;
            }
}

// ---------------------------------------------------------------------------
extern "C" void kernel_launch(void* const* d_in, const int* in_sizes, int n_in,
                              void* d_out, int out_size, void* d_ws, size_t ws_size,
                              hipStream_t stream)
{
    const float* x     = (const float*)d_in[0];
    const float* Wc    = (const float*)d_in[1];
    const float* bc    = (const float*)d_in[2];
    const float* Wa    = (const float*)d_in[3];
    const float* a_src = (const float*)d_in[4];
    const float* a_tgt = (const float*)d_in[5];
    const float* ba    = (const float*)d_in[6];
    const float* ln_g  = (const float*)d_in[7];
    const float* ln_b  = (const float*)d_in[8];
    const float* Wg    = (const float*)d_in[9];
    const float* bg    = (const float*)d_in[10];
    const float* Wp    = (const float*)d_in[11];
    const float* bp    = (const float*)d_in[12];

    float* out = (float*)d_out;
    // d_out doubles as scratch before the final write:
    short* supb = (short*)d_out;                               // support, later h (8.4MB)
    char* dsec  = (char*)d_out + (size_t)NR * HD * 2;
    float* es   = (float*)dsec;                                // NR*4 floats
    float* et   = es + (size_t)NR * NHEADS;                    // NR*4 floats

    char* w = (char*)d_ws;
    short* gsb = (short*)w;   w += (size_t)NR * HD * 2;        // gs1b then gs2b
    short* xb  = (short*)w;   w += (size_t)NR * HD * 2;        // bf16 x
    short* WcT = (short*)w;   w += 256 * 256 * 2;
    short* WaT = (short*)w;   w += 256 * 256 * 2;
    short* WpT = (short*)w;   w += 256 * 256 * 2;
    short* WgT = (short*)w;   w += 512 * 256 * 2;

    dim3 ggrid(HD / 64, NR / 64);   // (4, 256) = 1024 blocks

    // 0) weights transpose+cast, x cast
    prep_kernel<<<dim3(4096, 5), 256, 0, stream>>>(Wc, Wa, Wg, Wp, x, WcT, WaT, WgT, WpT, xb);
    // 1) support(bf16) = xb @ Wc
    gemm_bf<<<ggrid, 256, 0, stream>>>(xb, WcT, supb);
    // 2) gs1b = bf16(LN(stencil(support) + bc + x))
    conv_ln<<<NR / 4, 256, 0, stream>>>(supb, x, bc, ln_g, ln_b, gsb);
    // 3) h(bf16) = gs1b @ Wa, fused es/et dots
    gemm_dots<<<ggrid, 256, 0, stream>>>(gsb, WaT, a_src, a_tgt, supb, es, et);
    // 4) gs2b = bf16(LN(attn_agg + ba + x)), softmax inline
    attn_ln<<<NR / 4, 256, 0, stream>>>(supb, es, et, x, ba, ln_g, ln_b, gsb);
    // 5) out = x + sigmoid([x,gs2]@Wg+bg) * (gs2@Wp+bp)
    final_mfma<<<ggrid, 256, 0, stream>>>(x, xb, gsb, WgT, bg, WpT, bp, out);
}

// Round 6
// 92.161 us; speedup vs baseline: 1.3921x; 1.3921x over previous
//
#include <hip/hip_runtime.h>
#include <math.h>

#define HD 256
#define SEQ 4096
#define NR 16384
#define NHEADS 4
#define EPSV 1e-5f
#define LDP 72   // padded LDS row stride (elements) for 64-wide K tiles

typedef __attribute__((ext_vector_type(8))) short bf16x8;
typedef __attribute__((ext_vector_type(4))) float f32x4;

__device__ inline short f2bf(float f) {
    unsigned u = __float_as_uint(f);
    u += 0x7FFF + ((u >> 16) & 1);     // round-to-nearest-even
    return (short)(u >> 16);
}
__device__ inline float bf2f(short s) {
    return __uint_as_float(((unsigned)(unsigned short)s) << 16);
}

// Stage a [rows x 64] bf16 tile (row-major src, stride src_stride, origin
// row0/k0) into padded LDS (stride LDP). Coalesced 16B chunks, 256 threads.
__device__ inline void stage_tile(const short* __restrict__ src, int src_stride,
                                  int row0, int k0, short* lds, int rows)
{
    int t = threadIdx.x;
    int nchunk = (rows * 8) >> 8;          // rows*64 elems / (256 thr * 8 elems)
#pragma unroll
    for (int c = 0; c < 4; ++c) {
        if (c >= nchunk) break;
        int idx = c * 256 + t;
        int r = idx >> 3, kg = idx & 7;
        bf16x8 v = *(const bf16x8*)(src + (size_t)(row0 + r) * src_stride + k0 + kg * 8);
        *(bf16x8*)(lds + r * LDP + kg * 8) = v;
    }
}

// ---------------------------------------------------------------------------
// Prep: transpose+cast weights to bf16 (tasks 0-3) and cast x -> bf16 (task 4)
// ---------------------------------------------------------------------------
__global__ __launch_bounds__(256) void prep_kernel(
    const float* __restrict__ Wc, const float* __restrict__ Wa,
    const float* __restrict__ Wg, const float* __restrict__ Wp,
    const float* __restrict__ x,
    short* __restrict__ WcT, short* __restrict__ WaT,
    short* __restrict__ WgT, short* __restrict__ WpT,
    short* __restrict__ xb)
{
    int task = blockIdx.y;
    int idx = blockIdx.x * 256 + threadIdx.x;
    if (task == 4) {
        float4 v = ((const float4*)x)[idx];
        short4 o;
        o.x = f2bf(v.x); o.y = f2bf(v.y); o.z = f2bf(v.z); o.w = f2bf(v.w);
        ((short4*)xb)[idx] = o;
        return;
    }
    const float* W; short* Wt; int K;
    if (task == 0)      { W = Wc; Wt = WcT; K = 256; }
    else if (task == 1) { W = Wa; Wt = WaT; K = 256; }
    else if (task == 2) { W = Wg; Wt = WgT; K = 512; }
    else                { W = Wp; Wt = WpT; K = 256; }
    if (idx >= K * 256) return;
    int n = idx & 255, k = idx >> 8;
    Wt[n * K + k] = f2bf(W[idx]);
}

// ---------------------------------------------------------------------------
// LDS-staged MFMA GEMM: C_bf16[NR x 256] = A @ B (BT = B^T bf16, stride 256).
// Tile 128(M) x 64(N), BK=64, 4 M-split waves (32x64 out each), padded LDS.
// ---------------------------------------------------------------------------
__global__ __launch_bounds__(256) void gemm_bf(const short* __restrict__ A,
                                               const short* __restrict__ BT,
                                               short* __restrict__ C)
{
    __shared__ __align__(16) short lA[128 * LDP];
    __shared__ __align__(16) short lB[64 * LDP];
    int tid = threadIdx.x;
    int lane = tid & 63, wid = tid >> 6;
    int m0 = blockIdx.y * 128;
    int n0 = blockIdx.x * 64;
    int woff = wid * 32;
    int lm = lane & 15, lk = (lane >> 4) * 8;
    f32x4 acc[2][4] = {};
    for (int kt = 0; kt < 4; ++kt) {
        __syncthreads();
        stage_tile(A,  HD, m0, kt * 64, lA, 128);
        stage_tile(BT, HD, n0, kt * 64, lB, 64);
        __syncthreads();
#pragma unroll
        for (int kk2 = 0; kk2 < 64; kk2 += 32) {
            bf16x8 a[2], b[4];
#pragma unroll
            for (int i = 0; i < 2; ++i)
                a[i] = *(const bf16x8*)(lA + (woff + i * 16 + lm) * LDP + kk2 + lk);
#pragma unroll
            for (int j = 0; j < 4; ++j)
                b[j] = *(const bf16x8*)(lB + (j * 16 + lm) * LDP + kk2 + lk);
#pragma unroll
            for (int i = 0; i < 2; ++i)
#pragma unroll
                for (int j = 0; j < 4; ++j)
                    acc[i][j] = __builtin_amdgcn_mfma_f32_16x16x32_bf16(a[i], b[j], acc[i][j], 0, 0, 0);
        }
    }
    int rbase = (lane >> 4) * 4;
#pragma unroll
    for (int i = 0; i < 2; ++i)
#pragma unroll
        for (int j = 0; j < 4; ++j)
#pragma unroll
            for (int r = 0; r < 4; ++r)
                C[(size_t)(m0 + woff + i * 16 + rbase + r) * HD + n0 + j * 16 + lm] = f2bf(acc[i][j][r]);
}

// ---------------------------------------------------------------------------
// GEMM2 + fused es/et dots. N-tile 64 = exactly one head (head = blockIdx.x);
// each wave owns full 64-col row slices -> per-wave 16-lane dot reduction.
// ---------------------------------------------------------------------------
__global__ __launch_bounds__(256) void gemm_dots(const short* __restrict__ A,
                                                 const short* __restrict__ BT,
                                                 const float* __restrict__ a_src,
                                                 const float* __restrict__ a_tgt,
                                                 short* __restrict__ C,
                                                 float* __restrict__ es,
                                                 float* __restrict__ et)
{
    __shared__ __align__(16) short lA[128 * LDP];
    __shared__ __align__(16) short lB[64 * LDP];
    int tid = threadIdx.x;
    int lane = tid & 63, wid = tid >> 6;
    int m0 = blockIdx.y * 128;
    int n0 = blockIdx.x * 64;
    int woff = wid * 32;
    int lm = lane & 15, lk = (lane >> 4) * 8;
    f32x4 acc[2][4] = {};
    for (int kt = 0; kt < 4; ++kt) {
        __syncthreads();
        stage_tile(A,  HD, m0, kt * 64, lA, 128);
        stage_tile(BT, HD, n0, kt * 64, lB, 64);
        __syncthreads();
#pragma unroll
        for (int kk2 = 0; kk2 < 64; kk2 += 32) {
            bf16x8 a[2], b[4];
#pragma unroll
            for (int i = 0; i < 2; ++i)
                a[i] = *(const bf16x8*)(lA + (woff + i * 16 + lm) * LDP + kk2 + lk);
#pragma unroll
            for (int j = 0; j < 4; ++j)
                b[j] = *(const bf16x8*)(lB + (j * 16 + lm) * LDP + kk2 + lk);
#pragma unroll
            for (int i = 0; i < 2; ++i)
#pragma unroll
                for (int j = 0; j < 4; ++j)
                    acc[i][j] = __builtin_amdgcn_mfma_f32_16x16x32_bf16(a[i], b[j], acc[i][j], 0, 0, 0);
        }
    }
    int rbase = (lane >> 4) * 4;
#pragma unroll
    for (int i = 0; i < 2; ++i)
#pragma unroll
        for (int j = 0; j < 4; ++j)
#pragma unroll
            for (int r = 0; r < 4; ++r)
                C[(size_t)(m0 + woff + i * 16 + rbase + r) * HD + n0 + j * 16 + lm] = f2bf(acc[i][j][r]);

    // fused per-head dots (head = blockIdx.x)
    float as4[4], at4[4];
#pragma unroll
    for (int j = 0; j < 4; ++j) {
        as4[j] = a_src[n0 + j * 16 + lm];
        at4[j] = a_tgt[n0 + j * 16 + lm];
    }
#pragma unroll
    for (int i = 0; i < 2; ++i)
#pragma unroll
        for (int r = 0; r < 4; ++r) {
            float ps = 0.f, pt = 0.f;
#pragma unroll
            for (int j = 0; j < 4; ++j) {
                ps += acc[i][j][r] * as4[j];
                pt += acc[i][j][r] * at4[j];
            }
#pragma unroll
            for (int o = 1; o < 16; o <<= 1) {
                ps += __shfl_xor(ps, o, 64);
                pt += __shfl_xor(pt, o, 64);
            }
            if (lm == 0) {
                int row = m0 + woff + i * 16 + rbase + r;
                es[row * NHEADS + blockIdx.x] = ps;
                et[row * NHEADS + blockIdx.x] = pt;
            }
        }
}

// ---------------------------------------------------------------------------
// Layer 0: 15-tap stencil over bf16 support + bias + residual(bf16 xb) + LN.
// 1 wave = 1 row; lane owns 4 channels.
// ---------------------------------------------------------------------------
__global__ __launch_bounds__(256) void conv_ln(const short* __restrict__ sup,
                                               const short* __restrict__ xb,
                                               const float* __restrict__ bc,
                                               const float* __restrict__ g,
                                               const float* __restrict__ bb,
                                               short* __restrict__ out)
{
    int wv = threadIdx.x >> 6, lane = threadIdx.x & 63;
    int t = blockIdx.x * 4 + wv;
    int p = t & (SEQ - 1);
    int c0 = lane * 4;
    float a0 = 0.f, a1 = 0.f, a2 = 0.f, a3 = 0.f;
#pragma unroll
    for (int i = 0; i < 15; ++i) {
        int d = (i < 7) ? (i - 7) : (i - 6);
        int qp = p + d;
        if (qp >= 0 && qp < SEQ) {
            short4 s4 = *(const short4*)(sup + (size_t)(t + d) * HD + c0);
            float wd = 1.f / (1.f + (float)((d < 0) ? -d : d));
            a0 += wd * bf2f(s4.x); a1 += wd * bf2f(s4.y);
            a2 += wd * bf2f(s4.z); a3 += wd * bf2f(s4.w);
        }
    }
    short4 xv4 = *(const short4*)(xb + (size_t)t * HD + c0);
    float4 bcv = *(const float4*)(bc + c0);
    float v0 = a0 + bcv.x + bf2f(xv4.x), v1 = a1 + bcv.y + bf2f(xv4.y);
    float v2 = a2 + bcv.z + bf2f(xv4.z), v3 = a3 + bcv.w + bf2f(xv4.w);
    float s = v0 + v1 + v2 + v3;
    float q = v0 * v0 + v1 * v1 + v2 * v2 + v3 * v3;
#pragma unroll
    for (int o = 1; o < 64; o <<= 1) { s += __shfl_xor(s, o, 64); q += __shfl_xor(q, o, 64); }
    float mu = s * (1.f / HD);
    float var = q * (1.f / HD) - mu * mu;
    float inv = rsqrtf(var + EPSV);
    float4 gv = *(const float4*)(g + c0);
    float4 bv = *(const float4*)(bb + c0);
    short4 o4;
    o4.x = f2bf((v0 - mu) * inv * gv.x + bv.x);
    o4.y = f2bf((v1 - mu) * inv * gv.y + bv.y);
    o4.z = f2bf((v2 - mu) * inv * gv.z + bv.z);
    o4.w = f2bf((v3 - mu) * inv * gv.w + bv.w);
    *(short4*)(out + (size_t)t * HD + c0) = o4;
}

// ---------------------------------------------------------------------------
// Layer 1: inline per-head softmax + 15-tap aggregation + residual(bf16) + LN.
// 1 wave = 1 row.
// ---------------------------------------------------------------------------
__global__ __launch_bounds__(256) void attn_ln(const short* __restrict__ hb,
                                               const float* __restrict__ es,
                                               const float* __restrict__ et,
                                               const short* __restrict__ xb,
                                               const float* __restrict__ ba,
                                               const float* __restrict__ g,
                                               const float* __restrict__ bb,
                                               short* __restrict__ out)
{
    int wv = threadIdx.x >> 6, lane = threadIdx.x & 63;
    int t = blockIdx.x * 4 + wv;
    int p = t & (SEQ - 1);

    // --- inline softmax: 60 (tap,head) terms across lanes ---
    int tap = lane >> 2, hh = lane & 3;
    float lg = -1e30f, wd = 0.f;
    bool okk = false;
    if (tap < 15) {
        int d = (tap < 7) ? (tap - 7) : (tap - 6);
        int qp = p + d;
        okk = (qp >= 0) && (qp < SEQ);
        if (okk) {
            float l = es[(t + d) * NHEADS + hh] + et[t * NHEADS + hh];
            lg = (l > 0.f) ? l : 0.2f * l;
        }
        wd = 1.f / (1.f + (float)((d < 0) ? -d : d));
    }
    float m = lg;
#pragma unroll
    for (int o = 4; o < 64; o <<= 1) m = fmaxf(m, __shfl_xor(m, o, 64));
    float un = okk ? __expf(lg - m) * wd : 0.f;
    float den = un;
#pragma unroll
    for (int o = 4; o < 64; o <<= 1) den += __shfl_xor(den, o, 64);
    float alpha_l = un / (den + 1e-9f);

    int hd = lane >> 4;
    float al[15];
#pragma unroll
    for (int i = 0; i < 15; ++i) al[i] = __shfl(alpha_l, i * 4 + hd, 64);

    // --- aggregation ---
    int c0 = lane * 4;
    float a0 = 0.f, a1 = 0.f, a2 = 0.f, a3 = 0.f;
#pragma unroll
    for (int i = 0; i < 15; ++i) {
        int d = (i < 7) ? (i - 7) : (i - 6);
        int qp = p + d;
        if (qp >= 0 && qp < SEQ) {
            short4 s4 = *(const short4*)(hb + (size_t)(t + d) * HD + c0);
            a0 += al[i] * bf2f(s4.x); a1 += al[i] * bf2f(s4.y);
            a2 += al[i] * bf2f(s4.z); a3 += al[i] * bf2f(s4.w);
        }
    }
    short4 xv4 = *(const short4*)(xb + (size_t)t * HD + c0);
    float4 bav = *(const float4*)(ba + c0);
    float v0 = a0 + bav.x + bf2f(xv4.x), v1 = a1 + bav.y + bf2f(xv4.y);
    float v2 = a2 + bav.z + bf2f(xv4.z), v3 = a3 + bav.w + bf2f(xv4.w);
    float s = v0 + v1 + v2 + v3;
    float q = v0 * v0 + v1 * v1 + v2 * v2 + v3 * v3;
#pragma unroll
    for (int o = 1; o < 64; o <<= 1) { s += __shfl_xor(s, o, 64); q += __shfl_xor(q, o, 64); }
    float mu = s * (1.f / HD);
    float var = q * (1.f / HD) - mu * mu;
    float inv = rsqrtf(var + EPSV);
    float4 gv = *(const float4*)(g + c0);
    float4 bv = *(const float4*)(bb + c0);
    short4 o4;
    o4.x = f2bf((v0 - mu) * inv * gv.x + bv.x);
    o4.y = f2bf((v1 - mu) * inv * gv.y + bv.y);
    o4.z = f2bf((v2 - mu) * inv * gv.z + bv.z);
    o4.w = f2bf((v3 - mu) * inv * gv.w + bv.w);
    *(short4*)(out + (size_t)t * HD + c0) = o4;
}

// ---------------------------------------------------------------------------
// Final: gate = sigmoid(x@Wg_top + gs2@Wg_bot + bg); out = x + gate*(gs2@Wp+bp)
// LDS-staged: 2 A tiles (xb, gs2b) + 3 B tiles (Wg top/bot, Wp). 63KB LDS.
// ---------------------------------------------------------------------------
__global__ __launch_bounds__(256) void final_mfma(const float* __restrict__ x,
                                                  const short* __restrict__ xb,
                                                  const short* __restrict__ gs2b,
                                                  const short* __restrict__ WgT,
                                                  const float* __restrict__ bg,
                                                  const short* __restrict__ WpT,
                                                  const float* __restrict__ bp,
                                                  float* __restrict__ out)
{
    __shared__ __align__(16) short lX[128 * LDP];
    __shared__ __align__(16) short lG[128 * LDP];
    __shared__ __align__(16) short lB1[64 * LDP];
    __shared__ __align__(16) short lB2[64 * LDP];
    __shared__ __align__(16) short lB3[64 * LDP];
    int tid = threadIdx.x;
    int lane = tid & 63, wid = tid >> 6;
    int m0 = blockIdx.y * 128;
    int n0 = blockIdx.x * 64;
    int woff = wid * 32;
    int lm = lane & 15, lk = (lane >> 4) * 8;
    f32x4 accg[2][4] = {}, accp[2][4] = {};
    for (int kt = 0; kt < 4; ++kt) {
        int k0 = kt * 64;
        __syncthreads();
        stage_tile(xb,   HD,  m0, k0, lX, 128);
        stage_tile(gs2b, HD,  m0, k0, lG, 128);
        stage_tile(WgT,  512, n0, k0, lB1, 64);
        stage_tile(WgT,  512, n0, k0 + 256, lB2, 64);
        stage_tile(WpT,  HD,  n0, k0, lB3, 64);
        __syncthreads();
#pragma unroll
        for (int kk2 = 0; kk2 < 64; kk2 += 32) {
            bf16x8 ax[2], ag[2], b1[4], b2[4], b3[4];
#pragma unroll
            for (int i = 0; i < 2; ++i) {
                int ro = (woff + i * 16 + lm) * LDP + kk2 + lk;
                ax[i] = *(const bf16x8*)(lX + ro);
                ag[i] = *(const bf16x8*)(lG + ro);
            }
#pragma unroll
            for (int j = 0; j < 4; ++j) {
                int ro = (j * 16 + lm) * LDP + kk2 + lk;
                b1[j] = *(const bf16x8*)(lB1 + ro);
                b2[j] = *(const bf16x8*)(lB2 + ro);
                b3[j] = *(const bf16x8*)(lB3 + ro);
            }
#pragma unroll
            for (int i = 0; i < 2; ++i)
#pragma unroll
                for (int j = 0; j < 4; ++j) {
                    accg[i][j] = __builtin_amdgcn_mfma_f32_16x16x32_bf16(ax[i], b1[j], accg[i][j], 0, 0, 0);
                    accg[i][j] = __builtin_amdgcn_mfma_f32_16x16x32_bf16(ag[i], b2[j], accg[i][j], 0, 0, 0);
                    accp[i][j] = __builtin_amdgcn_mfma_f32_16x16x32_bf16(ag[i], b3[j], accp[i][j], 0, 0, 0);
                }
        }
    }
    int rbase = (lane >> 4) * 4;
#pragma unroll
    for (int i = 0; i < 2; ++i)
#pragma unroll
        for (int j = 0; j < 4; ++j)
#pragma unroll
            for (int r = 0; r < 4; ++r) {
                size_t m = (size_t)(m0 + woff + i * 16 + rbase + r);
                int n = n0 + j * 16 + lm;
                float gate = 1.f / (1.f + __expf(-(accg[i][j][r] + bg[n])));
                float pv = accp[i][j][r] + bp[n];
                out[m * HD + n] = x[m * HD + n] + gate * pv;
            }
}

// ---------------------------------------------------------------------------
extern "C" void kernel_launch(void* const* d_in, const int* in_sizes, int n_in,
                              void* d_out, int out_size, void* d_ws, size_t ws_size,
                              hipStream_t stream)
{
    const float* x     = (const float*)d_in[0];
    const float* Wc    = (const float*)d_in[1];
    const float* bc    = (const float*)d_in[2];
    const float* Wa    = (const float*)d_in[3];
    const float* a_src = (const float*)d_in[4];
    const float* a_tgt = (const float*)d_in[5];
    const float* ba    = (const float*)d_in[6];
    const float* ln_g  = (const float*)d_in[7];
    const float* ln_b  = (const float*)d_in[8];
    const float* Wg    = (const float*)d_in[9];
    const float* bg    = (const float*)d_in[10];
    const float* Wp    = (const float*)d_in[11];
    const float* bp    = (const float*)d_in[12];

    float* out = (float*)d_out;
    // d_out doubles as scratch before the final write:
    short* supb = (short*)d_out;                               // support, later h (8.4MB)
    char* dsec  = (char*)d_out + (size_t)NR * HD * 2;
    float* es   = (float*)dsec;                                // NR*4 floats
    float* et   = es + (size_t)NR * NHEADS;                    // NR*4 floats

    char* w = (char*)d_ws;
    short* gsb = (short*)w;   w += (size_t)NR * HD * 2;        // gs1b then gs2b
    short* xb  = (short*)w;   w += (size_t)NR * HD * 2;        // bf16 x
    short* WcT = (short*)w;   w += 256 * 256 * 2;
    short* WaT = (short*)w;   w += 256 * 256 * 2;
    short* WpT = (short*)w;   w += 256 * 256 * 2;
    short* WgT = (short*)w;   w += 512 * 256 * 2;

    dim3 ggrid(HD / 64, NR / 128);   // (4, 128) = 512 blocks

    // 0) weights transpose+cast, x cast
    prep_kernel<<<dim3(4096, 5), 256, 0, stream>>>(Wc, Wa, Wg, Wp, x, WcT, WaT, WgT, WpT, xb);
    // 1) support(bf16) = xb @ Wc
    gemm_bf<<<ggrid, 256, 0, stream>>>(xb, WcT, supb);
    // 2) gs1b = bf16(LN(stencil(support) + bc + x))
    conv_ln<<<NR / 4, 256, 0, stream>>>(supb, xb, bc, ln_g, ln_b, gsb);
    // 3) h(bf16) = gs1b @ Wa, fused es/et dots (blockIdx.x = head)
    gemm_dots<<<ggrid, 256, 0, stream>>>(gsb, WaT, a_src, a_tgt, supb, es, et);
    // 4) gs2b = bf16(LN(attn_agg + ba + x)), softmax inline
    attn_ln<<<NR / 4, 256, 0, stream>>>(supb, es, et, xb, ba, ln_g, ln_b, gsb);
    // 5) out = x + sigmoid([x,gs2]@Wg+bg) * (gs2@Wp+bp)
    final_mfma<<<ggrid, 256, 0, stream>>>(x, xb, gsb, WgT, bg, WpT, bp, out);
}

// Round 7
// 91.248 us; speedup vs baseline: 1.4060x; 1.0100x over previous
//
#include <hip/hip_runtime.h>
#include <math.h>

#define HD 256
#define SEQ 4096
#define NR 16384
#define NHEADS 4
#define EPSV 1e-5f
#define LDP 72   // padded LDS row stride (elements) for 64-wide K tiles

typedef __attribute__((ext_vector_type(8))) short bf16x8;
typedef __attribute__((ext_vector_type(4))) float f32x4;

__device__ inline short f2bf(float f) {
    unsigned u = __float_as_uint(f);
    u += 0x7FFF + ((u >> 16) & 1);     // round-to-nearest-even
    return (short)(u >> 16);
}
__device__ inline float bf2f(short s) {
    return __uint_as_float(((unsigned)(unsigned short)s) << 16);
}

// Stage a [rows x 64] bf16 tile into padded LDS. Coalesced 16B chunks.
__device__ inline void stage_tile(const short* __restrict__ src, int src_stride,
                                  int row0, int k0, short* lds, int rows)
{
    int t = threadIdx.x;
    int nchunk = (rows * 8) >> 8;
#pragma unroll
    for (int c = 0; c < 4; ++c) {
        if (c >= nchunk) break;
        int idx = c * 256 + t;
        int r = idx >> 3, kg = idx & 7;
        bf16x8 v = *(const bf16x8*)(src + (size_t)(row0 + r) * src_stride + k0 + kg * 8);
        *(bf16x8*)(lds + r * LDP + kg * 8) = v;
    }
}

// Stage a [128 x 64] bf16 tile applying a per-row LayerNorm affine:
// out = (z - mu)*inv*g[k] + b[k], computed from accumulated row stats.
__device__ inline void stage_tile_ln(const short* __restrict__ z, int row0, int k0,
                                     const float* __restrict__ musum,
                                     const float* __restrict__ sqsum,
                                     const float* __restrict__ g,
                                     const float* __restrict__ b,
                                     short* lds)
{
    int t = threadIdx.x;
#pragma unroll
    for (int c = 0; c < 4; ++c) {
        int idx = c * 256 + t;
        int r = idx >> 3, kg = idx & 7;
        int row = row0 + r;
        float s = musum[row], q = sqsum[row];
        float mu = s * (1.f / HD);
        float inv = rsqrtf(q * (1.f / HD) - mu * mu + EPSV);
        bf16x8 v = *(const bf16x8*)(z + (size_t)row * HD + k0 + kg * 8);
        float4 g0 = *(const float4*)(g + k0 + kg * 8);
        float4 g1 = *(const float4*)(g + k0 + kg * 8 + 4);
        float4 b0 = *(const float4*)(b + k0 + kg * 8);
        float4 b1 = *(const float4*)(b + k0 + kg * 8 + 4);
        bf16x8 o;
        o[0] = f2bf((bf2f(v[0]) - mu) * inv * g0.x + b0.x);
        o[1] = f2bf((bf2f(v[1]) - mu) * inv * g0.y + b0.y);
        o[2] = f2bf((bf2f(v[2]) - mu) * inv * g0.z + b0.z);
        o[3] = f2bf((bf2f(v[3]) - mu) * inv * g0.w + b0.w);
        o[4] = f2bf((bf2f(v[4]) - mu) * inv * g1.x + b1.x);
        o[5] = f2bf((bf2f(v[5]) - mu) * inv * g1.y + b1.y);
        o[6] = f2bf((bf2f(v[6]) - mu) * inv * g1.z + b1.z);
        o[7] = f2bf((bf2f(v[7]) - mu) * inv * g1.w + b1.w);
        *(bf16x8*)(lds + r * LDP + kg * 8) = o;
    }
}

// ---------------------------------------------------------------------------
// Prep: tasks 0-3 weight transpose+cast (LDS-tiled, coalesced both sides),
// task 4 x->bf16, task 5 y = stencil(x) bf16, task 6 zero LN stats.
// ---------------------------------------------------------------------------
__global__ __launch_bounds__(256) void prep_kernel(
    const float* __restrict__ Wc, const float* __restrict__ Wa,
    const float* __restrict__ Wg, const float* __restrict__ Wp,
    const float* __restrict__ x,
    short* __restrict__ WcT, short* __restrict__ WaT,
    short* __restrict__ WgT, short* __restrict__ WpT,
    short* __restrict__ xb, short* __restrict__ y,
    float* __restrict__ musum, float* __restrict__ sqsum)
{
    int task = blockIdx.y;
    int bx = blockIdx.x;
    int t = threadIdx.x;
    if (task == 4) {                       // xb cast
        int idx = bx * 256 + t;
        float4 v = ((const float4*)x)[idx];
        short4 o;
        o.x = f2bf(v.x); o.y = f2bf(v.y); o.z = f2bf(v.z); o.w = f2bf(v.w);
        ((short4*)xb)[idx] = o;
        return;
    }
    if (task == 5) {                       // y = stencil(x), fp32 taps
        int idx = bx * 256 + t;            // NR*64 jobs
        int row = idx >> 6, c0 = (idx & 63) * 4;
        int p = row & (SEQ - 1);
        float a0 = 0.f, a1 = 0.f, a2 = 0.f, a3 = 0.f;
#pragma unroll
        for (int i = 0; i < 15; ++i) {
            int d = (i < 7) ? (i - 7) : (i - 6);
            int qp = p + d;
            if (qp >= 0 && qp < SEQ) {
                float4 v = *(const float4*)(x + (size_t)(row + d) * HD + c0);
                float wd = 1.f / (1.f + (float)((d < 0) ? -d : d));
                a0 += wd * v.x; a1 += wd * v.y; a2 += wd * v.z; a3 += wd * v.w;
            }
        }
        short4 o;
        o.x = f2bf(a0); o.y = f2bf(a1); o.z = f2bf(a2); o.w = f2bf(a3);
        *(short4*)(y + (size_t)row * HD + c0) = o;
        return;
    }
    if (task == 6) {                       // zero stats
        int idx = bx * 256 + t;
        if (idx < NR) { musum[idx] = 0.f; sqsum[idx] = 0.f; }
        return;
    }
    // tasks 0-3: W^T via LDS tile (64x64)
    __shared__ float lds[64][65];
    const float* W; short* Wt; int K;
    if (task == 0)      { W = Wc; Wt = WcT; K = 256; }
    else if (task == 1) { W = Wa; Wt = WaT; K = 256; }
    else if (task == 2) { W = Wg; Wt = WgT; K = 512; }
    else                { W = Wp; Wt = WpT; K = 256; }
    int ntiles = (K >> 6) * 4;
    if (bx >= ntiles) return;
    int k0 = (bx >> 2) * 64, n0 = (bx & 3) * 64;
    int ty = t >> 6, tx = t & 63;
#pragma unroll
    for (int s = 0; s < 16; ++s) {
        int r = s * 4 + ty;
        lds[r][tx] = W[(size_t)(k0 + r) * 256 + n0 + tx];
    }
    __syncthreads();
#pragma unroll
    for (int s = 0; s < 16; ++s) {
        int rn = s * 4 + ty;
        Wt[(size_t)(n0 + rn) * K + k0 + tx] = f2bf(lds[tx][rn]);
    }
}

// ---------------------------------------------------------------------------
// GEMM1: z = y @ Wc + bc + xb (residual), write z bf16; accumulate per-row
// LN stats (sum, sumsq) via 16-lane shuffles + atomics.
// Tile 128(M) x 64(N), BK=64, 4 M-split waves.
// ---------------------------------------------------------------------------
__global__ __launch_bounds__(256) void gemm1z(const short* __restrict__ A,
                                              const short* __restrict__ BT,
                                              const short* __restrict__ xb,
                                              const float* __restrict__ bc,
                                              short* __restrict__ Z,
                                              float* __restrict__ musum,
                                              float* __restrict__ sqsum)
{
    __shared__ __align__(16) short lA[128 * LDP];
    __shared__ __align__(16) short lB[64 * LDP];
    int tid = threadIdx.x;
    int lane = tid & 63, wid = tid >> 6;
    int m0 = blockIdx.y * 128;
    int n0 = blockIdx.x * 64;
    int woff = wid * 32;
    int lm = lane & 15, lk = (lane >> 4) * 8;
    f32x4 acc[2][4] = {};
    for (int kt = 0; kt < 4; ++kt) {
        __syncthreads();
        stage_tile(A,  HD, m0, kt * 64, lA, 128);
        stage_tile(BT, HD, n0, kt * 64, lB, 64);
        __syncthreads();
#pragma unroll
        for (int kk2 = 0; kk2 < 64; kk2 += 32) {
            bf16x8 a[2], b[4];
#pragma unroll
            for (int i = 0; i < 2; ++i)
                a[i] = *(const bf16x8*)(lA + (woff + i * 16 + lm) * LDP + kk2 + lk);
#pragma unroll
            for (int j = 0; j < 4; ++j)
                b[j] = *(const bf16x8*)(lB + (j * 16 + lm) * LDP + kk2 + lk);
#pragma unroll
            for (int i = 0; i < 2; ++i)
#pragma unroll
                for (int j = 0; j < 4; ++j)
                    acc[i][j] = __builtin_amdgcn_mfma_f32_16x16x32_bf16(a[i], b[j], acc[i][j], 0, 0, 0);
        }
    }
    int rbase = (lane >> 4) * 4;
#pragma unroll
    for (int i = 0; i < 2; ++i)
#pragma unroll
        for (int r = 0; r < 4; ++r) {
            int row = m0 + woff + i * 16 + rbase + r;
            float s = 0.f, q = 0.f;
#pragma unroll
            for (int j = 0; j < 4; ++j) {
                int n = n0 + j * 16 + lm;
                float z = acc[i][j][r] + bc[n] + bf2f(xb[(size_t)row * HD + n]);
                Z[(size_t)row * HD + n] = f2bf(z);
                s += z; q += z * z;
            }
#pragma unroll
            for (int o = 1; o < 16; o <<= 1) {
                s += __shfl_xor(s, o, 64);
                q += __shfl_xor(q, o, 64);
            }
            if (lm == 0) {
                atomicAdd(&musum[row], s);
                atomicAdd(&sqsum[row], q);
            }
        }
}

// ---------------------------------------------------------------------------
// GEMM2: h = LN(z) @ Wa (LN applied per-row during A staging) + fused es/et.
// N-tile 64 = exactly one head (head = blockIdx.x).
// ---------------------------------------------------------------------------
__global__ __launch_bounds__(256) void gemm_dots2(const short* __restrict__ Z,
                                                  const short* __restrict__ BT,
                                                  const float* __restrict__ musum,
                                                  const float* __restrict__ sqsum,
                                                  const float* __restrict__ lng,
                                                  const float* __restrict__ lnb,
                                                  const float* __restrict__ a_src,
                                                  const float* __restrict__ a_tgt,
                                                  short* __restrict__ C,
                                                  float* __restrict__ es,
                                                  float* __restrict__ et)
{
    __shared__ __align__(16) short lA[128 * LDP];
    __shared__ __align__(16) short lB[64 * LDP];
    int tid = threadIdx.x;
    int lane = tid & 63, wid = tid >> 6;
    int m0 = blockIdx.y * 128;
    int n0 = blockIdx.x * 64;
    int woff = wid * 32;
    int lm = lane & 15, lk = (lane >> 4) * 8;
    f32x4 acc[2][4] = {};
    for (int kt = 0; kt < 4; ++kt) {
        __syncthreads();
        stage_tile_ln(Z, m0, kt * 64, musum, sqsum, lng, lnb, lA);
        stage_tile(BT, HD, n0, kt * 64, lB, 64);
        __syncthreads();
#pragma unroll
        for (int kk2 = 0; kk2 < 64; kk2 += 32) {
            bf16x8 a[2], b[4];
#pragma unroll
            for (int i = 0; i < 2; ++i)
                a[i] = *(const bf16x8*)(lA + (woff + i * 16 + lm) * LDP + kk2 + lk);
#pragma unroll
            for (int j = 0; j < 4; ++j)
                b[j] = *(const bf16x8*)(lB + (j * 16 + lm) * LDP + kk2 + lk);
#pragma unroll
            for (int i = 0; i < 2; ++i)
#pragma unroll
                for (int j = 0; j < 4; ++j)
                    acc[i][j] = __builtin_amdgcn_mfma_f32_16x16x32_bf16(a[i], b[j], acc[i][j], 0, 0, 0);
        }
    }
    int rbase = (lane >> 4) * 4;
#pragma unroll
    for (int i = 0; i < 2; ++i)
#pragma unroll
        for (int j = 0; j < 4; ++j)
#pragma unroll
            for (int r = 0; r < 4; ++r)
                C[(size_t)(m0 + woff + i * 16 + rbase + r) * HD + n0 + j * 16 + lm] = f2bf(acc[i][j][r]);

    float as4[4], at4[4];
#pragma unroll
    for (int j = 0; j < 4; ++j) {
        as4[j] = a_src[n0 + j * 16 + lm];
        at4[j] = a_tgt[n0 + j * 16 + lm];
    }
#pragma unroll
    for (int i = 0; i < 2; ++i)
#pragma unroll
        for (int r = 0; r < 4; ++r) {
            float ps = 0.f, pt = 0.f;
#pragma unroll
            for (int j = 0; j < 4; ++j) {
                ps += acc[i][j][r] * as4[j];
                pt += acc[i][j][r] * at4[j];
            }
#pragma unroll
            for (int o = 1; o < 16; o <<= 1) {
                ps += __shfl_xor(ps, o, 64);
                pt += __shfl_xor(pt, o, 64);
            }
            if (lm == 0) {
                int row = m0 + woff + i * 16 + rbase + r;
                es[row * NHEADS + blockIdx.x] = ps;
                et[row * NHEADS + blockIdx.x] = pt;
            }
        }
}

// ---------------------------------------------------------------------------
// Layer 1: inline per-head softmax + 15-tap aggregation + residual(bf16) + LN.
// 1 wave = 1 row.
// ---------------------------------------------------------------------------
__global__ __launch_bounds__(256) void attn_ln(const short* __restrict__ hb,
                                               const float* __restrict__ es,
                                               const float* __restrict__ et,
                                               const short* __restrict__ xb,
                                               const float* __restrict__ ba,
                                               const float* __restrict__ g,
                                               const float* __restrict__ bb,
                                               short* __restrict__ out)
{
    int wv = threadIdx.x >> 6, lane = threadIdx.x & 63;
    int t = blockIdx.x * 4 + wv;
    int p = t & (SEQ - 1);

    int tap = lane >> 2, hh = lane & 3;
    float lg = -1e30f, wd = 0.f;
    bool okk = false;
    if (tap < 15) {
        int d = (tap < 7) ? (tap - 7) : (tap - 6);
        int qp = p + d;
        okk = (qp >= 0) && (qp < SEQ);
        if (okk) {
            float l = es[(t + d) * NHEADS + hh] + et[t * NHEADS + hh];
            lg = (l > 0.f) ? l : 0.2f * l;
        }
        wd = 1.f / (1.f + (float)((d < 0) ? -d : d));
    }
    float m = lg;
#pragma unroll
    for (int o = 4; o < 64; o <<= 1) m = fmaxf(m, __shfl_xor(m, o, 64));
    float un = okk ? __expf(lg - m) * wd : 0.f;
    float den = un;
#pragma unroll
    for (int o = 4; o < 64; o <<= 1) den += __shfl_xor(den, o, 64);
    float alpha_l = un / (den + 1e-9f);

    int hd = lane >> 4;
    float al[15];
#pragma unroll
    for (int i = 0; i < 15; ++i) al[i] = __shfl(alpha_l, i * 4 + hd, 64);

    int c0 = lane * 4;
    float a0 = 0.f, a1 = 0.f, a2 = 0.f, a3 = 0.f;
#pragma unroll
    for (int i = 0; i < 15; ++i) {
        int d = (i < 7) ? (i - 7) : (i - 6);
        int qp = p + d;
        if (qp >= 0 && qp < SEQ) {
            short4 s4 = *(const short4*)(hb + (size_t)(t + d) * HD + c0);
            a0 += al[i] * bf2f(s4.x); a1 += al[i] * bf2f(s4.y);
            a2 += al[i] * bf2f(s4.z); a3 += al[i] * bf2f(s4.w);
        }
    }
    short4 xv4 = *(const short4*)(xb + (size_t)t * HD + c0);
    float4 bav = *(const float4*)(ba + c0);
    float v0 = a0 + bav.x + bf2f(xv4.x), v1 = a1 + bav.y + bf2f(xv4.y);
    float v2 = a2 + bav.z + bf2f(xv4.z), v3 = a3 + bav.w + bf2f(xv4.w);
    float s = v0 + v1 + v2 + v3;
    float q = v0 * v0 + v1 * v1 + v2 * v2 + v3 * v3;
#pragma unroll
    for (int o = 1; o < 64; o <<= 1) { s += __shfl_xor(s, o, 64); q += __shfl_xor(q, o, 64); }
    float mu = s * (1.f / HD);
    float var = q * (1.f / HD) - mu * mu;
    float inv = rsqrtf(var + EPSV);
    float4 gv = *(const float4*)(g + c0);
    float4 bv = *(const float4*)(bb + c0);
    short4 o4;
    o4.x = f2bf((v0 - mu) * inv * gv.x + bv.x);
    o4.y = f2bf((v1 - mu) * inv * gv.y + bv.y);
    o4.z = f2bf((v2 - mu) * inv * gv.z + bv.z);
    o4.w = f2bf((v3 - mu) * inv * gv.w + bv.w);
    *(short4*)(out + (size_t)t * HD + c0) = o4;
}

// ---------------------------------------------------------------------------
// Final: gate = sigmoid(x@Wg_top + gs2@Wg_bot + bg); out = x + gate*(gs2@Wp+bp)
// Residual from xb (bf16). LDS-staged, 5 tiles.
// ---------------------------------------------------------------------------
__global__ __launch_bounds__(256) void final_mfma(const short* __restrict__ xb,
                                                  const short* __restrict__ gs2b,
                                                  const short* __restrict__ WgT,
                                                  const float* __restrict__ bg,
                                                  const short* __restrict__ WpT,
                                                  const float* __restrict__ bp,
                                                  float* __restrict__ out)
{
    __shared__ __align__(16) short lX[128 * LDP];
    __shared__ __align__(16) short lG[128 * LDP];
    __shared__ __align__(16) short lB1[64 * LDP];
    __shared__ __align__(16) short lB2[64 * LDP];
    __shared__ __align__(16) short lB3[64 * LDP];
    int tid = threadIdx.x;
    int lane = tid & 63, wid = tid >> 6;
    int m0 = blockIdx.y * 128;
    int n0 = blockIdx.x * 64;
    int woff = wid * 32;
    int lm = lane & 15, lk = (lane >> 4) * 8;
    f32x4 accg[2][4] = {}, accp[2][4] = {};
    for (int kt = 0; kt < 4; ++kt) {
        int k0 = kt * 64;
        __syncthreads();
        stage_tile(xb,   HD,  m0, k0, lX, 128);
        stage_tile(gs2b, HD,  m0, k0, lG, 128);
        stage_tile(WgT,  512, n0, k0, lB1, 64);
        stage_tile(WgT,  512, n0, k0 + 256, lB2, 64);
        stage_tile(WpT,  HD,  n0, k0, lB3, 64);
        __syncthreads();
#pragma unroll
        for (int kk2 = 0; kk2 < 64; kk2 += 32) {
            bf16x8 ax[2], ag[2], b1[4], b2[4], b3[4];
#pragma unroll
            for (int i = 0; i < 2; ++i) {
                int ro = (woff + i * 16 + lm) * LDP + kk2 + lk;
                ax[i] = *(const bf16x8*)(lX + ro);
                ag[i] = *(const bf16x8*)(lG + ro);
            }
#pragma unroll
            for (int j = 0; j < 4; ++j) {
                int ro = (j * 16 + lm) * LDP + kk2 + lk;
                b1[j] = *(const bf16x8*)(lB1 + ro);
                b2[j] = *(const bf16x8*)(lB2 + ro);
                b3[j] = *(const bf16x8*)(lB3 + ro);
            }
#pragma unroll
            for (int i = 0; i < 2; ++i)
#pragma unroll
                for (int j = 0; j < 4; ++j) {
                    accg[i][j] = __builtin_amdgcn_mfma_f32_16x16x32_bf16(ax[i], b1[j], accg[i][j], 0, 0, 0);
                    accg[i][j] = __builtin_amdgcn_mfma_f32_16x16x32_bf16(ag[i], b2[j], accg[i][j], 0, 0, 0);
                    accp[i][j] = __builtin_amdgcn_mfma_f32_16x16x32_bf16(ag[i], b3[j], accp[i][j], 0, 0, 0);
                }
        }
    }
    int rbase = (lane >> 4) * 4;
#pragma unroll
    for (int i = 0; i < 2; ++i)
#pragma unroll
        for (int j = 0; j < 4; ++j)
#pragma unroll
            for (int r = 0; r < 4; ++r) {
                size_t m = (size_t)(m0 + woff + i * 16 + rbase + r);
                int n = n0 + j * 16 + lm;
                float gate = 1.f / (1.f + __expf(-(accg[i][j][r] + bg[n])));
                float pv = accp[i][j][r] + bp[n];
                out[m * HD + n] = bf2f(xb[m * HD + n]) + gate * pv;
            }
}

// ---------------------------------------------------------------------------
extern "C" void kernel_launch(void* const* d_in, const int* in_sizes, int n_in,
                              void* d_out, int out_size, void* d_ws, size_t ws_size,
                              hipStream_t stream)
{
    const float* x     = (const float*)d_in[0];
    const float* Wc    = (const float*)d_in[1];
    const float* bc    = (const float*)d_in[2];
    const float* Wa    = (const float*)d_in[3];
    const float* a_src = (const float*)d_in[4];
    const float* a_tgt = (const float*)d_in[5];
    const float* ba    = (const float*)d_in[6];
    const float* ln_g  = (const float*)d_in[7];
    const float* ln_b  = (const float*)d_in[8];
    const float* Wg    = (const float*)d_in[9];
    const float* bg    = (const float*)d_in[10];
    const float* Wp    = (const float*)d_in[11];
    const float* bp    = (const float*)d_in[12];

    float* out = (float*)d_out;
    // d_out scratch (dead before final writes): h (8MB) + es/et
    short* hb  = (short*)d_out;
    char* dsec = (char*)d_out + (size_t)NR * HD * 2;
    float* es  = (float*)dsec;
    float* et  = es + (size_t)NR * NHEADS;

    char* w = (char*)d_ws;
    short* y   = (short*)w;   w += (size_t)NR * HD * 2;   // stencil(x) bf16
    short* zb  = (short*)w;   w += (size_t)NR * HD * 2;   // z, later gs2
    short* xb  = (short*)w;   w += (size_t)NR * HD * 2;   // bf16 x
    short* WcT = (short*)w;   w += 256 * 256 * 2;
    short* WaT = (short*)w;   w += 256 * 256 * 2;
    short* WpT = (short*)w;   w += 256 * 256 * 2;
    short* WgT = (short*)w;   w += 512 * 256 * 2;
    float* musum = (float*)w; w += (size_t)NR * 4;
    float* sqsum = (float*)w; w += (size_t)NR * 4;

    dim3 ggrid(HD / 64, NR / 128);   // (4, 128) = 512 blocks

    // 0) weights^T, xb, y = stencil(x), zero stats
    prep_kernel<<<dim3(4096, 7), 256, 0, stream>>>(Wc, Wa, Wg, Wp, x,
                                                   WcT, WaT, WgT, WpT, xb, y, musum, sqsum);
    // 1) z = y@Wc + bc + xb; LN stats
    gemm1z<<<ggrid, 256, 0, stream>>>(y, WcT, xb, bc, zb, musum, sqsum);
    // 2) h = LN(z)@Wa (LN in staging) + es/et dots
    gemm_dots2<<<ggrid, 256, 0, stream>>>(zb, WaT, musum, sqsum, ln_g, ln_b,
                                          a_src, a_tgt, hb, es, et);
    // 3) gs2 = bf16(LN(attn_agg + ba + xb))   (z dead -> reuse zb)
    attn_ln<<<NR / 4, 256, 0, stream>>>(hb, es, et, xb, ba, ln_g, ln_b, zb);
    // 4) out = xb + sigmoid([xb,gs2]@Wg+bg) * (gs2@Wp+bp)
    final_mfma<<<ggrid, 256, 0, stream>>>(xb, zb, WgT, bg, WpT, bp, out);
}

// Round 8
// 87.372 us; speedup vs baseline: 1.4684x; 1.0444x over previous
//
#include <hip/hip_runtime.h>
#include <math.h>

#define HD 256
#define SEQ 4096
#define NR 16384
#define NHEADS 4
#define EPSV 1e-5f
#define LDP 72    // padded LDS row stride for GEMM K-tiles
#define SROWS 32  // stencil rows per block
#define SHALO 15  // 7 below + 8 above
#define SLDP 264  // stencil LDS row stride (elements)

typedef __attribute__((ext_vector_type(8))) short bf16x8;
typedef __attribute__((ext_vector_type(4))) float f32x4;

__device__ inline short f2bf(float f) {
    unsigned u = __float_as_uint(f);
    u += 0x7FFF + ((u >> 16) & 1);     // round-to-nearest-even
    return (short)(u >> 16);
}
__device__ inline float bf2f(short s) {
    return __uint_as_float(((unsigned)(unsigned short)s) << 16);
}

// Stage a [rows x 64] bf16 tile into padded LDS. Coalesced 16B chunks.
__device__ inline void stage_tile(const short* __restrict__ src, int src_stride,
                                  int row0, int k0, short* lds, int rows)
{
    int t = threadIdx.x;
    int nchunk = (rows * 8) >> 8;
#pragma unroll
    for (int c = 0; c < 4; ++c) {
        if (c >= nchunk) break;
        int idx = c * 256 + t;
        int r = idx >> 3, kg = idx & 7;
        bf16x8 v = *(const bf16x8*)(src + (size_t)(row0 + r) * src_stride + k0 + kg * 8);
        *(bf16x8*)(lds + r * LDP + kg * 8) = v;
    }
}

// Stage a [128 x 64] bf16 tile applying per-row LayerNorm affine.
__device__ inline void stage_tile_ln(const short* __restrict__ z, int row0, int k0,
                                     const float* __restrict__ musum,
                                     const float* __restrict__ sqsum,
                                     const float* __restrict__ g,
                                     const float* __restrict__ b,
                                     short* lds)
{
    int t = threadIdx.x;
#pragma unroll
    for (int c = 0; c < 4; ++c) {
        int idx = c * 256 + t;
        int r = idx >> 3, kg = idx & 7;
        int row = row0 + r;
        float s = musum[row], q = sqsum[row];
        float mu = s * (1.f / HD);
        float inv = rsqrtf(q * (1.f / HD) - mu * mu + EPSV);
        bf16x8 v = *(const bf16x8*)(z + (size_t)row * HD + k0 + kg * 8);
        float4 g0 = *(const float4*)(g + k0 + kg * 8);
        float4 g1 = *(const float4*)(g + k0 + kg * 8 + 4);
        float4 b0 = *(const float4*)(b + k0 + kg * 8);
        float4 b1 = *(const float4*)(b + k0 + kg * 8 + 4);
        bf16x8 o;
        o[0] = f2bf((bf2f(v[0]) - mu) * inv * g0.x + b0.x);
        o[1] = f2bf((bf2f(v[1]) - mu) * inv * g0.y + b0.y);
        o[2] = f2bf((bf2f(v[2]) - mu) * inv * g0.z + b0.z);
        o[3] = f2bf((bf2f(v[3]) - mu) * inv * g0.w + b0.w);
        o[4] = f2bf((bf2f(v[4]) - mu) * inv * g1.x + b1.x);
        o[5] = f2bf((bf2f(v[5]) - mu) * inv * g1.y + b1.y);
        o[6] = f2bf((bf2f(v[6]) - mu) * inv * g1.z + b1.z);
        o[7] = f2bf((bf2f(v[7]) - mu) * inv * g1.w + b1.w);
        *(bf16x8*)(lds + r * LDP + kg * 8) = o;
    }
}

// ---------------------------------------------------------------------------
// Prep: tasks 0-3 weight transpose+cast (LDS-tiled); task 4 zero LN stats.
// ---------------------------------------------------------------------------
__global__ __launch_bounds__(256) void prep_kernel(
    const float* __restrict__ Wc, const float* __restrict__ Wa,
    const float* __restrict__ Wg, const float* __restrict__ Wp,
    short* __restrict__ WcT, short* __restrict__ WaT,
    short* __restrict__ WgT, short* __restrict__ WpT,
    float* __restrict__ musum, float* __restrict__ sqsum)
{
    int task = blockIdx.y;
    int bx = blockIdx.x;
    int t = threadIdx.x;
    if (task == 4) {                       // zero stats: NR*2 floats / (64*256)
        int idx = bx * 256 + t;
        if (idx < NR) { musum[idx] = 0.f; sqsum[idx] = 0.f; }
        return;
    }
    __shared__ float lds[64][65];
    const float* W; short* Wt; int K;
    if (task == 0)      { W = Wc; Wt = WcT; K = 256; }
    else if (task == 1) { W = Wa; Wt = WaT; K = 256; }
    else if (task == 2) { W = Wg; Wt = WgT; K = 512; }
    else                { W = Wp; Wt = WpT; K = 256; }
    int ntiles = (K >> 6) * 4;
    if (bx >= ntiles) return;
    int k0 = (bx >> 2) * 64, n0 = (bx & 3) * 64;
    int ty = t >> 6, tx = t & 63;
#pragma unroll
    for (int s = 0; s < 16; ++s) {
        int r = s * 4 + ty;
        lds[r][tx] = W[(size_t)(k0 + r) * 256 + n0 + tx];
    }
    __syncthreads();
#pragma unroll
    for (int s = 0; s < 16; ++s) {
        int rn = s * 4 + ty;
        Wt[(size_t)(n0 + rn) * K + k0 + tx] = f2bf(lds[tx][rn]);
    }
}

// ---------------------------------------------------------------------------
// Stencil + cast, LDS-tiled: block owns 32 rows; stages 47 rows of fp32 x as
// bf16 into LDS once; writes xb (own rows) and y = 15-tap stencil.
// ---------------------------------------------------------------------------
__global__ __launch_bounds__(256) void stencil_cast(const float* __restrict__ x,
                                                    short* __restrict__ xb,
                                                    short* __restrict__ y)
{
    __shared__ short lH[(SROWS + SHALO) * SLDP];
    int t0 = blockIdx.x * SROWS;
    int batch_base = t0 & ~(SEQ - 1);
    int t = threadIdx.x;
    // stage 47 rows x 256 ch (fp32 -> bf16)
    for (int i = t; i < (SROWS + SHALO) * 64; i += 256) {
        int r = i >> 6, c4 = (i & 63) * 4;
        int grow = t0 - 7 + r;
        short4 o4 = {0, 0, 0, 0};
        if (grow >= batch_base && grow < batch_base + SEQ) {
            float4 v = *(const float4*)(x + (size_t)grow * HD + c4);
            o4.x = f2bf(v.x); o4.y = f2bf(v.y); o4.z = f2bf(v.z); o4.w = f2bf(v.w);
        }
        *(short4*)(lH + r * SLDP + c4) = o4;
    }
    __syncthreads();
    // write xb for own rows
    for (int i = t; i < SROWS * 64; i += 256) {
        int r = i >> 6, c4 = (i & 63) * 4;
        *(short4*)(xb + (size_t)(t0 + r) * HD + c4) =
            *(const short4*)(lH + (r + 7) * SLDP + c4);
    }
    // stencil: wave per row, lane owns 4 channels
    int wv = t >> 6, lane = t & 63;
    int c0 = lane * 4;
    for (int rr = wv; rr < SROWS; rr += 4) {
        float a0 = 0.f, a1 = 0.f, a2 = 0.f, a3 = 0.f;
#pragma unroll
        for (int i = 0; i < 15; ++i) {
            int d = (i < 7) ? (i - 7) : (i - 6);   // -7..-1, 1..8
            float wd = 1.f / (1.f + (float)((d < 0) ? -d : d));
            short4 s4 = *(const short4*)(lH + (rr + 7 + d) * SLDP + c0);
            a0 += wd * bf2f(s4.x); a1 += wd * bf2f(s4.y);
            a2 += wd * bf2f(s4.z); a3 += wd * bf2f(s4.w);
        }
        short4 o;
        o.x = f2bf(a0); o.y = f2bf(a1); o.z = f2bf(a2); o.w = f2bf(a3);
        *(short4*)(y + (size_t)(t0 + rr) * HD + c0) = o;
    }
}

// ---------------------------------------------------------------------------
// GEMM1: z = y @ Wc + bc + xb, write z bf16; accumulate per-row LN stats.
// ---------------------------------------------------------------------------
__global__ __launch_bounds__(256) void gemm1z(const short* __restrict__ A,
                                              const short* __restrict__ BT,
                                              const short* __restrict__ xb,
                                              const float* __restrict__ bc,
                                              short* __restrict__ Z,
                                              float* __restrict__ musum,
                                              float* __restrict__ sqsum)
{
    __shared__ __align__(16) short lA[128 * LDP];
    __shared__ __align__(16) short lB[64 * LDP];
    int tid = threadIdx.x;
    int lane = tid & 63, wid = tid >> 6;
    int m0 = blockIdx.y * 128;
    int n0 = blockIdx.x * 64;
    int woff = wid * 32;
    int lm = lane & 15, lk = (lane >> 4) * 8;
    f32x4 acc[2][4] = {};
    for (int kt = 0; kt < 4; ++kt) {
        __syncthreads();
        stage_tile(A,  HD, m0, kt * 64, lA, 128);
        stage_tile(BT, HD, n0, kt * 64, lB, 64);
        __syncthreads();
#pragma unroll
        for (int kk2 = 0; kk2 < 64; kk2 += 32) {
            bf16x8 a[2], b[4];
#pragma unroll
            for (int i = 0; i < 2; ++i)
                a[i] = *(const bf16x8*)(lA + (woff + i * 16 + lm) * LDP + kk2 + lk);
#pragma unroll
            for (int j = 0; j < 4; ++j)
                b[j] = *(const bf16x8*)(lB + (j * 16 + lm) * LDP + kk2 + lk);
#pragma unroll
            for (int i = 0; i < 2; ++i)
#pragma unroll
                for (int j = 0; j < 4; ++j)
                    acc[i][j] = __builtin_amdgcn_mfma_f32_16x16x32_bf16(a[i], b[j], acc[i][j], 0, 0, 0);
        }
    }
    int rbase = (lane >> 4) * 4;
#pragma unroll
    for (int i = 0; i < 2; ++i)
#pragma unroll
        for (int r = 0; r < 4; ++r) {
            int row = m0 + woff + i * 16 + rbase + r;
            float s = 0.f, q = 0.f;
#pragma unroll
            for (int j = 0; j < 4; ++j) {
                int n = n0 + j * 16 + lm;
                float z = acc[i][j][r] + bc[n] + bf2f(xb[(size_t)row * HD + n]);
                Z[(size_t)row * HD + n] = f2bf(z);
                s += z; q += z * z;
            }
#pragma unroll
            for (int o = 1; o < 16; o <<= 1) {
                s += __shfl_xor(s, o, 64);
                q += __shfl_xor(q, o, 64);
            }
            if (lm == 0) {
                atomicAdd(&musum[row], s);
                atomicAdd(&sqsum[row], q);
            }
        }
}

// ---------------------------------------------------------------------------
// GEMM2: h = LN(z) @ Wa (LN in A-staging) + fused es/et (head = blockIdx.x).
// ---------------------------------------------------------------------------
__global__ __launch_bounds__(256) void gemm_dots2(const short* __restrict__ Z,
                                                  const short* __restrict__ BT,
                                                  const float* __restrict__ musum,
                                                  const float* __restrict__ sqsum,
                                                  const float* __restrict__ lng,
                                                  const float* __restrict__ lnb,
                                                  const float* __restrict__ a_src,
                                                  const float* __restrict__ a_tgt,
                                                  short* __restrict__ C,
                                                  float* __restrict__ es,
                                                  float* __restrict__ et)
{
    __shared__ __align__(16) short lA[128 * LDP];
    __shared__ __align__(16) short lB[64 * LDP];
    int tid = threadIdx.x;
    int lane = tid & 63, wid = tid >> 6;
    int m0 = blockIdx.y * 128;
    int n0 = blockIdx.x * 64;
    int woff = wid * 32;
    int lm = lane & 15, lk = (lane >> 4) * 8;
    f32x4 acc[2][4] = {};
    for (int kt = 0; kt < 4; ++kt) {
        __syncthreads();
        stage_tile_ln(Z, m0, kt * 64, musum, sqsum, lng, lnb, lA);
        stage_tile(BT, HD, n0, kt * 64, lB, 64);
        __syncthreads();
#pragma unroll
        for (int kk2 = 0; kk2 < 64; kk2 += 32) {
            bf16x8 a[2], b[4];
#pragma unroll
            for (int i = 0; i < 2; ++i)
                a[i] = *(const bf16x8*)(lA + (woff + i * 16 + lm) * LDP + kk2 + lk);
#pragma unroll
            for (int j = 0; j < 4; ++j)
                b[j] = *(const bf16x8*)(lB + (j * 16 + lm) * LDP + kk2 + lk);
#pragma unroll
            for (int i = 0; i < 2; ++i)
#pragma unroll
                for (int j = 0; j < 4; ++j)
                    acc[i][j] = __builtin_amdgcn_mfma_f32_16x16x32_bf16(a[i], b[j], acc[i][j], 0, 0, 0);
        }
    }
    int rbase = (lane >> 4) * 4;
#pragma unroll
    for (int i = 0; i < 2; ++i)
#pragma unroll
        for (int j = 0; j < 4; ++j)
#pragma unroll
            for (int r = 0; r < 4; ++r)
                C[(size_t)(m0 + woff + i * 16 + rbase + r) * HD + n0 + j * 16 + lm] = f2bf(acc[i][j][r]);

    float as4[4], at4[4];
#pragma unroll
    for (int j = 0; j < 4; ++j) {
        as4[j] = a_src[n0 + j * 16 + lm];
        at4[j] = a_tgt[n0 + j * 16 + lm];
    }
#pragma unroll
    for (int i = 0; i < 2; ++i)
#pragma unroll
        for (int r = 0; r < 4; ++r) {
            float ps = 0.f, pt = 0.f;
#pragma unroll
            for (int j = 0; j < 4; ++j) {
                ps += acc[i][j][r] * as4[j];
                pt += acc[i][j][r] * at4[j];
            }
#pragma unroll
            for (int o = 1; o < 16; o <<= 1) {
                ps += __shfl_xor(ps, o, 64);
                pt += __shfl_xor(pt, o, 64);
            }
            if (lm == 0) {
                int row = m0 + woff + i * 16 + rbase + r;
                es[row * NHEADS + blockIdx.x] = ps;
                et[row * NHEADS + blockIdx.x] = pt;
            }
        }
}

// ---------------------------------------------------------------------------
// Layer 1, LDS-tiled: block owns 32 rows; stages 47 rows of h into LDS once.
// Per row (wave): inline per-head softmax + 15-tap LDS aggregation + LN.
// ---------------------------------------------------------------------------
__global__ __launch_bounds__(256) void attn_ln(const short* __restrict__ hb,
                                               const float* __restrict__ es,
                                               const float* __restrict__ et,
                                               const short* __restrict__ xb,
                                               const float* __restrict__ ba,
                                               const float* __restrict__ g,
                                               const float* __restrict__ bb,
                                               short* __restrict__ out)
{
    __shared__ short lH[(SROWS + SHALO) * SLDP];
    int t0 = blockIdx.x * SROWS;
    int batch_base = t0 & ~(SEQ - 1);
    int t = threadIdx.x;
    for (int i = t; i < (SROWS + SHALO) * 64; i += 256) {
        int r = i >> 6, c4 = (i & 63) * 4;
        int grow = t0 - 7 + r;
        short4 v = {0, 0, 0, 0};
        if (grow >= batch_base && grow < batch_base + SEQ)
            v = *(const short4*)(hb + (size_t)grow * HD + c4);
        *(short4*)(lH + r * SLDP + c4) = v;
    }
    __syncthreads();

    int wv = t >> 6, lane = t & 63;
    int tap = lane >> 2, hh = lane & 3;
    int hd = lane >> 4;
    int c0 = lane * 4;
    for (int rr = wv; rr < SROWS; rr += 4) {
        int trow = t0 + rr;
        int p = trow & (SEQ - 1);
        // --- softmax: 60 (tap,head) terms across lanes ---
        float lg = -1e30f, wd = 0.f;
        bool okk = false;
        if (tap < 15) {
            int d = (tap < 7) ? (tap - 7) : (tap - 6);
            int qp = p + d;
            okk = (qp >= 0) && (qp < SEQ);
            if (okk) {
                float l = es[(trow + d) * NHEADS + hh] + et[trow * NHEADS + hh];
                lg = (l > 0.f) ? l : 0.2f * l;
            }
            wd = 1.f / (1.f + (float)((d < 0) ? -d : d));
        }
        float m = lg;
#pragma unroll
        for (int o = 4; o < 64; o <<= 1) m = fmaxf(m, __shfl_xor(m, o, 64));
        float un = okk ? __expf(lg - m) * wd : 0.f;
        float den = un;
#pragma unroll
        for (int o = 4; o < 64; o <<= 1) den += __shfl_xor(den, o, 64);
        float alpha_l = un / (den + 1e-9f);

        float al[15];
#pragma unroll
        for (int i = 0; i < 15; ++i) al[i] = __shfl(alpha_l, i * 4 + hd, 64);

        // --- aggregation from LDS (halo rows are zero; alpha=0 there) ---
        float a0 = 0.f, a1 = 0.f, a2 = 0.f, a3 = 0.f;
#pragma unroll
        for (int i = 0; i < 15; ++i) {
            int d = (i < 7) ? (i - 7) : (i - 6);
            short4 s4 = *(const short4*)(lH + (rr + 7 + d) * SLDP + c0);
            a0 += al[i] * bf2f(s4.x); a1 += al[i] * bf2f(s4.y);
            a2 += al[i] * bf2f(s4.z); a3 += al[i] * bf2f(s4.w);
        }
        short4 xv4 = *(const short4*)(xb + (size_t)trow * HD + c0);
        float4 bav = *(const float4*)(ba + c0);
        float v0 = a0 + bav.x + bf2f(xv4.x), v1 = a1 + bav.y + bf2f(xv4.y);
        float v2 = a2 + bav.z + bf2f(xv4.z), v3 = a3 + bav.w + bf2f(xv4.w);
        float s = v0 + v1 + v2 + v3;
        float q = v0 * v0 + v1 * v1 + v2 * v2 + v3 * v3;
#pragma unroll
        for (int o = 1; o < 64; o <<= 1) { s += __shfl_xor(s, o, 64); q += __shfl_xor(q, o, 64); }
        float mu = s * (1.f / HD);
        float var = q * (1.f / HD) - mu * mu;
        float inv = rsqrtf(var + EPSV);
        float4 gv = *(const float4*)(g + c0);
        float4 bv = *(const float4*)(bb + c0);
        short4 o4;
        o4.x = f2bf((v0 - mu) * inv * gv.x + bv.x);
        o4.y = f2bf((v1 - mu) * inv * gv.y + bv.y);
        o4.z = f2bf((v2 - mu) * inv * gv.z + bv.z);
        o4.w = f2bf((v3 - mu) * inv * gv.w + bv.w);
        *(short4*)(out + (size_t)trow * HD + c0) = o4;
    }
}

// ---------------------------------------------------------------------------
// Final: gate = sigmoid(x@Wg_top + gs2@Wg_bot + bg); out = x + gate*(gs2@Wp+bp)
// ---------------------------------------------------------------------------
__global__ __launch_bounds__(256) void final_mfma(const short* __restrict__ xb,
                                                  const short* __restrict__ gs2b,
                                                  const short* __restrict__ WgT,
                                                  const float* __restrict__ bg,
                                                  const short* __restrict__ WpT,
                                                  const float* __restrict__ bp,
                                                  float* __restrict__ out)
{
    __shared__ __align__(16) short lX[128 * LDP];
    __shared__ __align__(16) short lG[128 * LDP];
    __shared__ __align__(16) short lB1[64 * LDP];
    __shared__ __align__(16) short lB2[64 * LDP];
    __shared__ __align__(16) short lB3[64 * LDP];
    int tid = threadIdx.x;
    int lane = tid & 63, wid = tid >> 6;
    int m0 = blockIdx.y * 128;
    int n0 = blockIdx.x * 64;
    int woff = wid * 32;
    int lm = lane & 15, lk = (lane >> 4) * 8;
    f32x4 accg[2][4] = {}, accp[2][4] = {};
    for (int kt = 0; kt < 4; ++kt) {
        int k0 = kt * 64;
        __syncthreads();
        stage_tile(xb,   HD,  m0, k0, lX, 128);
        stage_tile(gs2b, HD,  m0, k0, lG, 128);
        stage_tile(WgT,  512, n0, k0, lB1, 64);
        stage_tile(WgT,  512, n0, k0 + 256, lB2, 64);
        stage_tile(WpT,  HD,  n0, k0, lB3, 64);
        __syncthreads();
#pragma unroll
        for (int kk2 = 0; kk2 < 64; kk2 += 32) {
            bf16x8 ax[2], ag[2], b1[4], b2[4], b3[4];
#pragma unroll
            for (int i = 0; i < 2; ++i) {
                int ro = (woff + i * 16 + lm) * LDP + kk2 + lk;
                ax[i] = *(const bf16x8*)(lX + ro);
                ag[i] = *(const bf16x8*)(lG + ro);
            }
#pragma unroll
            for (int j = 0; j < 4; ++j) {
                int ro = (j * 16 + lm) * LDP + kk2 + lk;
                b1[j] = *(const bf16x8*)(lB1 + ro);
                b2[j] = *(const bf16x8*)(lB2 + ro);
                b3[j] = *(const bf16x8*)(lB3 + ro);
            }
#pragma unroll
            for (int i = 0; i < 2; ++i)
#pragma unroll
                for (int j = 0; j < 4; ++j) {
                    accg[i][j] = __builtin_amdgcn_mfma_f32_16x16x32_bf16(ax[i], b1[j], accg[i][j], 0, 0, 0);
                    accg[i][j] = __builtin_amdgcn_mfma_f32_16x16x32_bf16(ag[i], b2[j], accg[i][j], 0, 0, 0);
                    accp[i][j] = __builtin_amdgcn_mfma_f32_16x16x32_bf16(ag[i], b3[j], accp[i][j], 0, 0, 0);
                }
        }
    }
    int rbase = (lane >> 4) * 4;
#pragma unroll
    for (int i = 0; i < 2; ++i)
#pragma unroll
        for (int j = 0; j < 4; ++j)
#pragma unroll
            for (int r = 0; r < 4; ++r) {
                size_t m = (size_t)(m0 + woff + i * 16 + rbase + r);
                int n = n0 + j * 16 + lm;
                float gate = 1.f / (1.f + __expf(-(accg[i][j][r] + bg[n])));
                float pv = accp[i][j][r] + bp[n];
                out[m * HD + n] = bf2f(xb[m * HD + n]) + gate * pv;
            }
}

// ---------------------------------------------------------------------------
extern "C" void kernel_launch(void* const* d_in, const int* in_sizes, int n_in,
                              void* d_out, int out_size, void* d_ws, size_t ws_size,
                              hipStream_t stream)
{
    const float* x     = (const float*)d_in[0];
    const float* Wc    = (const float*)d_in[1];
    const float* bc    = (const float*)d_in[2];
    const float* Wa    = (const float*)d_in[3];
    const float* a_src = (const float*)d_in[4];
    const float* a_tgt = (const float*)d_in[5];
    const float* ba    = (const float*)d_in[6];
    const float* ln_g  = (const float*)d_in[7];
    const float* ln_b  = (const float*)d_in[8];
    const float* Wg    = (const float*)d_in[9];
    const float* bg    = (const float*)d_in[10];
    const float* Wp    = (const float*)d_in[11];
    const float* bp    = (const float*)d_in[12];

    float* out = (float*)d_out;
    // d_out scratch (dead before final writes): h (8.4MB) + es/et
    short* hb  = (short*)d_out;
    char* dsec = (char*)d_out + (size_t)NR * HD * 2;
    float* es  = (float*)dsec;
    float* et  = es + (size_t)NR * NHEADS;

    char* w = (char*)d_ws;
    short* y   = (short*)w;   w += (size_t)NR * HD * 2;   // stencil(x) bf16
    short* zb  = (short*)w;   w += (size_t)NR * HD * 2;   // z, later gs2
    short* xb  = (short*)w;   w += (size_t)NR * HD * 2;   // bf16 x
    short* WcT = (short*)w;   w += 256 * 256 * 2;
    short* WaT = (short*)w;   w += 256 * 256 * 2;
    short* WpT = (short*)w;   w += 256 * 256 * 2;
    short* WgT = (short*)w;   w += 512 * 256 * 2;
    float* musum = (float*)w; w += (size_t)NR * 4;
    float* sqsum = (float*)w; w += (size_t)NR * 4;

    dim3 ggrid(HD / 64, NR / 128);   // (4, 128) = 512 blocks

    // 0) weights^T + zero stats
    prep_kernel<<<dim3(64, 5), 256, 0, stream>>>(Wc, Wa, Wg, Wp,
                                                 WcT, WaT, WgT, WpT, musum, sqsum);
    // 1) xb = bf16(x); y = stencil(x)  (LDS-tiled, one pass over x)
    stencil_cast<<<NR / SROWS, 256, 0, stream>>>(x, xb, y);
    // 2) z = y@Wc + bc + xb; LN stats
    gemm1z<<<ggrid, 256, 0, stream>>>(y, WcT, xb, bc, zb, musum, sqsum);
    // 3) h = LN(z)@Wa (LN in staging) + es/et dots
    gemm_dots2<<<ggrid, 256, 0, stream>>>(zb, WaT, musum, sqsum, ln_g, ln_b,
                                          a_src, a_tgt, hb, es, et);
    // 4) gs2 = bf16(LN(attn_agg + ba + xb))  (LDS-tiled; z dead -> reuse zb)
    attn_ln<<<NR / SROWS, 256, 0, stream>>>(hb, es, et, xb, ba, ln_g, ln_b, zb);
    // 5) out = xb + sigmoid([xb,gs2]@Wg+bg) * (gs2@Wp+bp)
    final_mfma<<<ggrid, 256, 0, stream>>>(xb, zb, WgT, bg, WpT, bp, out);
}

// Round 9
// 81.363 us; speedup vs baseline: 1.5769x; 1.0739x over previous
//
#include <hip/hip_runtime.h>
#include <math.h>

#define HD 256
#define SEQ 4096
#define NR 16384
#define NHEADS 4
#define EPSV 1e-5f
#define LDP 72    // padded LDS row stride for GEMM K-tiles (144B = 9*16B, 2-way bank max)
#define SROWS 32  // stencil rows per block
#define SHALO 15  // 7 below + 8 above
#define SLDP 264  // stencil LDS row stride (elements)

typedef __attribute__((ext_vector_type(8))) short bf16x8;
typedef __attribute__((ext_vector_type(4))) float f32x4;

__device__ inline short f2bf(float f) {
    unsigned u = __float_as_uint(f);
    u += 0x7FFF + ((u >> 16) & 1);     // round-to-nearest-even
    return (short)(u >> 16);
}
__device__ inline float bf2f(short s) {
    return __uint_as_float(((unsigned)(unsigned short)s) << 16);
}

// Stage a [rows x 64] bf16 tile into padded LDS. Coalesced 16B chunks.
__device__ inline void stage_tile(const short* __restrict__ src, int src_stride,
                                  int row0, int k0, short* lds, int rows)
{
    int t = threadIdx.x;
    int nchunk = rows >> 5;            // rows*64 / (256thr*8el)
#pragma unroll
    for (int c = 0; c < 4; ++c) {
        if (c >= nchunk) break;
        int idx = c * 256 + t;
        int r = idx >> 3, kg = idx & 7;
        bf16x8 v = *(const bf16x8*)(src + (size_t)(row0 + r) * src_stride + k0 + kg * 8);
        *(bf16x8*)(lds + r * LDP + kg * 8) = v;
    }
}

// Stage a [rows x 64] bf16 tile applying per-row LayerNorm affine.
__device__ inline void stage_tile_ln(const short* __restrict__ z, int row0, int k0,
                                     const float* __restrict__ musum,
                                     const float* __restrict__ sqsum,
                                     const float* __restrict__ g,
                                     const float* __restrict__ b,
                                     short* lds, int rows)
{
    int t = threadIdx.x;
    int nchunk = rows >> 5;
#pragma unroll
    for (int c = 0; c < 4; ++c) {
        if (c >= nchunk) break;
        int idx = c * 256 + t;
        int r = idx >> 3, kg = idx & 7;
        int row = row0 + r;
        float s = musum[row], q = sqsum[row];
        float mu = s * (1.f / HD);
        float inv = rsqrtf(q * (1.f / HD) - mu * mu + EPSV);
        bf16x8 v = *(const bf16x8*)(z + (size_t)row * HD + k0 + kg * 8);
        float4 g0 = *(const float4*)(g + k0 + kg * 8);
        float4 g1 = *(const float4*)(g + k0 + kg * 8 + 4);
        float4 b0 = *(const float4*)(b + k0 + kg * 8);
        float4 b1 = *(const float4*)(b + k0 + kg * 8 + 4);
        bf16x8 o;
        o[0] = f2bf((bf2f(v[0]) - mu) * inv * g0.x + b0.x);
        o[1] = f2bf((bf2f(v[1]) - mu) * inv * g0.y + b0.y);
        o[2] = f2bf((bf2f(v[2]) - mu) * inv * g0.z + b0.z);
        o[3] = f2bf((bf2f(v[3]) - mu) * inv * g0.w + b0.w);
        o[4] = f2bf((bf2f(v[4]) - mu) * inv * g1.x + b1.x);
        o[5] = f2bf((bf2f(v[5]) - mu) * inv * g1.y + b1.y);
        o[6] = f2bf((bf2f(v[6]) - mu) * inv * g1.z + b1.z);
        o[7] = f2bf((bf2f(v[7]) - mu) * inv * g1.w + b1.w);
        *(bf16x8*)(lds + r * LDP + kg * 8) = o;
    }
}

// ---------------------------------------------------------------------------
// Merged prep + stencil. grid (512, 6):
//  task 0: stencil+cast (bx < 512): xb = bf16(x), y = 15-tap stencil(x)
//  tasks 1-4: weight transpose+cast (Wc/Wa/Wg/Wp)
//  task 5: zero LN stats
// ---------------------------------------------------------------------------
__global__ __launch_bounds__(256) void prep_stencil(
    const float* __restrict__ x,
    const float* __restrict__ Wc, const float* __restrict__ Wa,
    const float* __restrict__ Wg, const float* __restrict__ Wp,
    short* __restrict__ xb, short* __restrict__ y,
    short* __restrict__ WcT, short* __restrict__ WaT,
    short* __restrict__ WgT, short* __restrict__ WpT,
    float* __restrict__ musum, float* __restrict__ sqsum)
{
    __shared__ __align__(16) char smem[(SROWS + SHALO) * SLDP * 2];
    int task = blockIdx.y;
    int bx = blockIdx.x;
    int t = threadIdx.x;

    if (task == 0) {                   // stencil + cast
        short* lH = (short*)smem;
        int t0 = bx * SROWS;
        int batch_base = t0 & ~(SEQ - 1);
        for (int i = t; i < (SROWS + SHALO) * 64; i += 256) {
            int r = i >> 6, c4 = (i & 63) * 4;
            int grow = t0 - 7 + r;
            short4 o4 = {0, 0, 0, 0};
            if (grow >= batch_base && grow < batch_base + SEQ) {
                float4 v = *(const float4*)(x + (size_t)grow * HD + c4);
                o4.x = f2bf(v.x); o4.y = f2bf(v.y); o4.z = f2bf(v.z); o4.w = f2bf(v.w);
            }
            *(short4*)(lH + r * SLDP + c4) = o4;
        }
        __syncthreads();
        for (int i = t; i < SROWS * 64; i += 256) {
            int r = i >> 6, c4 = (i & 63) * 4;
            *(short4*)(xb + (size_t)(t0 + r) * HD + c4) =
                *(const short4*)(lH + (r + 7) * SLDP + c4);
        }
        int wv = t >> 6, lane = t & 63;
        int c0 = lane * 4;
        for (int rr = wv; rr < SROWS; rr += 4) {
            float a0 = 0.f, a1 = 0.f, a2 = 0.f, a3 = 0.f;
#pragma unroll
            for (int i = 0; i < 15; ++i) {
                int d = (i < 7) ? (i - 7) : (i - 6);   // -7..-1, 1..8
                float wd = 1.f / (1.f + (float)((d < 0) ? -d : d));
                short4 s4 = *(const short4*)(lH + (rr + 7 + d) * SLDP + c0);
                a0 += wd * bf2f(s4.x); a1 += wd * bf2f(s4.y);
                a2 += wd * bf2f(s4.z); a3 += wd * bf2f(s4.w);
            }
            short4 o;
            o.x = f2bf(a0); o.y = f2bf(a1); o.z = f2bf(a2); o.w = f2bf(a3);
            *(short4*)(y + (size_t)(t0 + rr) * HD + c0) = o;
        }
        return;
    }
    if (task == 5) {                   // zero stats
        int idx = bx * 256 + t;
        if (idx < NR) { musum[idx] = 0.f; sqsum[idx] = 0.f; }
        return;
    }
    // tasks 1-4: W^T via LDS tile (64x64)
    float (*lds)[65] = (float (*)[65])smem;
    const float* W; short* Wt; int K;
    if (task == 1)      { W = Wc; Wt = WcT; K = 256; }
    else if (task == 2) { W = Wa; Wt = WaT; K = 256; }
    else if (task == 3) { W = Wg; Wt = WgT; K = 512; }
    else                { W = Wp; Wt = WpT; K = 256; }
    int ntiles = (K >> 6) * 4;
    if (bx >= ntiles) return;
    int k0 = (bx >> 2) * 64, n0 = (bx & 3) * 64;
    int ty = t >> 6, tx = t & 63;
#pragma unroll
    for (int s = 0; s < 16; ++s) {
        int r = s * 4 + ty;
        lds[r][tx] = W[(size_t)(k0 + r) * 256 + n0 + tx];
    }
    __syncthreads();
#pragma unroll
    for (int s = 0; s < 16; ++s) {
        int rn = s * 4 + ty;
        Wt[(size_t)(n0 + rn) * K + k0 + tx] = f2bf(lds[tx][rn]);
    }
}

// ---------------------------------------------------------------------------
// GEMM1: z = y @ Wc + bc + xb, write z bf16; accumulate per-row LN stats.
// Tile 64(M) x 64(N), BK=64, 4 waves (16 rows each). Grid (4,256)=1024.
// ---------------------------------------------------------------------------
__global__ __launch_bounds__(256) void gemm1z(const short* __restrict__ A,
                                              const short* __restrict__ BT,
                                              const short* __restrict__ xb,
                                              const float* __restrict__ bc,
                                              short* __restrict__ Z,
                                              float* __restrict__ musum,
                                              float* __restrict__ sqsum)
{
    __shared__ __align__(16) short lA[64 * LDP];
    __shared__ __align__(16) short lB[64 * LDP];
    int tid = threadIdx.x;
    int lane = tid & 63, wid = tid >> 6;
    int m0 = blockIdx.y * 64;
    int n0 = blockIdx.x * 64;
    int wrow = wid * 16;
    int lm = lane & 15, lk = (lane >> 4) * 8;
    f32x4 acc[4] = {};
    for (int kt = 0; kt < 4; ++kt) {
        __syncthreads();
        stage_tile(A,  HD, m0, kt * 64, lA, 64);
        stage_tile(BT, HD, n0, kt * 64, lB, 64);
        __syncthreads();
#pragma unroll
        for (int kk2 = 0; kk2 < 64; kk2 += 32) {
            bf16x8 a = *(const bf16x8*)(lA + (wrow + lm) * LDP + kk2 + lk);
            bf16x8 b[4];
#pragma unroll
            for (int j = 0; j < 4; ++j)
                b[j] = *(const bf16x8*)(lB + (j * 16 + lm) * LDP + kk2 + lk);
#pragma unroll
            for (int j = 0; j < 4; ++j)
                acc[j] = __builtin_amdgcn_mfma_f32_16x16x32_bf16(a, b[j], acc[j], 0, 0, 0);
        }
    }
    int rbase = (lane >> 4) * 4;
#pragma unroll
    for (int r = 0; r < 4; ++r) {
        int row = m0 + wrow + rbase + r;
        float s = 0.f, q = 0.f;
#pragma unroll
        for (int j = 0; j < 4; ++j) {
            int n = n0 + j * 16 + lm;
            float z = acc[j][r] + bc[n] + bf2f(xb[(size_t)row * HD + n]);
            Z[(size_t)row * HD + n] = f2bf(z);
            s += z; q += z * z;
        }
#pragma unroll
        for (int o = 1; o < 16; o <<= 1) {
            s += __shfl_xor(s, o, 64);
            q += __shfl_xor(q, o, 64);
        }
        if (lm == 0) {
            atomicAdd(&musum[row], s);
            atomicAdd(&sqsum[row], q);
        }
    }
}

// ---------------------------------------------------------------------------
// GEMM2: h = LN(z) @ Wa (LN in A-staging) + fused es/et (head = blockIdx.x).
// Tile 64x64, grid (4,256).
// ---------------------------------------------------------------------------
__global__ __launch_bounds__(256) void gemm_dots2(const short* __restrict__ Z,
                                                  const short* __restrict__ BT,
                                                  const float* __restrict__ musum,
                                                  const float* __restrict__ sqsum,
                                                  const float* __restrict__ lng,
                                                  const float* __restrict__ lnb,
                                                  const float* __restrict__ a_src,
                                                  const float* __restrict__ a_tgt,
                                                  short* __restrict__ C,
                                                  float* __restrict__ es,
                                                  float* __restrict__ et)
{
    __shared__ __align__(16) short lA[64 * LDP];
    __shared__ __align__(16) short lB[64 * LDP];
    int tid = threadIdx.x;
    int lane = tid & 63, wid = tid >> 6;
    int m0 = blockIdx.y * 64;
    int n0 = blockIdx.x * 64;
    int wrow = wid * 16;
    int lm = lane & 15, lk = (lane >> 4) * 8;
    f32x4 acc[4] = {};
    for (int kt = 0; kt < 4; ++kt) {
        __syncthreads();
        stage_tile_ln(Z, m0, kt * 64, musum, sqsum, lng, lnb, lA, 64);
        stage_tile(BT, HD, n0, kt * 64, lB, 64);
        __syncthreads();
#pragma unroll
        for (int kk2 = 0; kk2 < 64; kk2 += 32) {
            bf16x8 a = *(const bf16x8*)(lA + (wrow + lm) * LDP + kk2 + lk);
            bf16x8 b[4];
#pragma unroll
            for (int j = 0; j < 4; ++j)
                b[j] = *(const bf16x8*)(lB + (j * 16 + lm) * LDP + kk2 + lk);
#pragma unroll
            for (int j = 0; j < 4; ++j)
                acc[j] = __builtin_amdgcn_mfma_f32_16x16x32_bf16(a, b[j], acc[j], 0, 0, 0);
        }
    }
    int rbase = (lane >> 4) * 4;
#pragma unroll
    for (int j = 0; j < 4; ++j)
#pragma unroll
        for (int r = 0; r < 4; ++r)
            C[(size_t)(m0 + wrow + rbase + r) * HD + n0 + j * 16 + lm] = f2bf(acc[j][r]);

    float as4[4], at4[4];
#pragma unroll
    for (int j = 0; j < 4; ++j) {
        as4[j] = a_src[n0 + j * 16 + lm];
        at4[j] = a_tgt[n0 + j * 16 + lm];
    }
#pragma unroll
    for (int r = 0; r < 4; ++r) {
        float ps = 0.f, pt = 0.f;
#pragma unroll
        for (int j = 0; j < 4; ++j) {
            ps += acc[j][r] * as4[j];
            pt += acc[j][r] * at4[j];
        }
#pragma unroll
        for (int o = 1; o < 16; o <<= 1) {
            ps += __shfl_xor(ps, o, 64);
            pt += __shfl_xor(pt, o, 64);
        }
        if (lm == 0) {
            int row = m0 + wrow + rbase + r;
            es[row * NHEADS + blockIdx.x] = ps;
            et[row * NHEADS + blockIdx.x] = pt;
        }
    }
}

// ---------------------------------------------------------------------------
// Layer 1, LDS-tiled: block owns 32 rows; stages 47 rows of h into LDS once.
// Per row (wave): inline per-head softmax + 15-tap LDS aggregation + LN.
// ---------------------------------------------------------------------------
__global__ __launch_bounds__(256) void attn_ln(const short* __restrict__ hb,
                                               const float* __restrict__ es,
                                               const float* __restrict__ et,
                                               const short* __restrict__ xb,
                                               const float* __restrict__ ba,
                                               const float* __restrict__ g,
                                               const float* __restrict__ bb,
                                               short* __restrict__ out)
{
    __shared__ short lH[(SROWS + SHALO) * SLDP];
    int t0 = blockIdx.x * SROWS;
    int batch_base = t0 & ~(SEQ - 1);
    int t = threadIdx.x;
    for (int i = t; i < (SROWS + SHALO) * 64; i += 256) {
        int r = i >> 6, c4 = (i & 63) * 4;
        int grow = t0 - 7 + r;
        short4 v = {0, 0, 0, 0};
        if (grow >= batch_base && grow < batch_base + SEQ)
            v = *(const short4*)(hb + (size_t)grow * HD + c4);
        *(short4*)(lH + r * SLDP + c4) = v;
    }
    __syncthreads();

    int wv = t >> 6, lane = t & 63;
    int tap = lane >> 2, hh = lane & 3;
    int hd = lane >> 4;
    int c0 = lane * 4;
    for (int rr = wv; rr < SROWS; rr += 4) {
        int trow = t0 + rr;
        int p = trow & (SEQ - 1);
        float lg = -1e30f, wd = 0.f;
        bool okk = false;
        if (tap < 15) {
            int d = (tap < 7) ? (tap - 7) : (tap - 6);
            int qp = p + d;
            okk = (qp >= 0) && (qp < SEQ);
            if (okk) {
                float l = es[(trow + d) * NHEADS + hh] + et[trow * NHEADS + hh];
                lg = (l > 0.f) ? l : 0.2f * l;
            }
            wd = 1.f / (1.f + (float)((d < 0) ? -d : d));
        }
        float m = lg;
#pragma unroll
        for (int o = 4; o < 64; o <<= 1) m = fmaxf(m, __shfl_xor(m, o, 64));
        float un = okk ? __expf(lg - m) * wd : 0.f;
        float den = un;
#pragma unroll
        for (int o = 4; o < 64; o <<= 1) den += __shfl_xor(den, o, 64);
        float alpha_l = un / (den + 1e-9f);

        float al[15];
#pragma unroll
        for (int i = 0; i < 15; ++i) al[i] = __shfl(alpha_l, i * 4 + hd, 64);

        float a0 = 0.f, a1 = 0.f, a2 = 0.f, a3 = 0.f;
#pragma unroll
        for (int i = 0; i < 15; ++i) {
            int d = (i < 7) ? (i - 7) : (i - 6);
            short4 s4 = *(const short4*)(lH + (rr + 7 + d) * SLDP + c0);
            a0 += al[i] * bf2f(s4.x); a1 += al[i] * bf2f(s4.y);
            a2 += al[i] * bf2f(s4.z); a3 += al[i] * bf2f(s4.w);
        }
        short4 xv4 = *(const short4*)(xb + (size_t)trow * HD + c0);
        float4 bav = *(const float4*)(ba + c0);
        float v0 = a0 + bav.x + bf2f(xv4.x), v1 = a1 + bav.y + bf2f(xv4.y);
        float v2 = a2 + bav.z + bf2f(xv4.z), v3 = a3 + bav.w + bf2f(xv4.w);
        float s = v0 + v1 + v2 + v3;
        float q = v0 * v0 + v1 * v1 + v2 * v2 + v3 * v3;
#pragma unroll
        for (int o = 1; o < 64; o <<= 1) { s += __shfl_xor(s, o, 64); q += __shfl_xor(q, o, 64); }
        float mu = s * (1.f / HD);
        float var = q * (1.f / HD) - mu * mu;
        float inv = rsqrtf(var + EPSV);
        float4 gv = *(const float4*)(g + c0);
        float4 bv = *(const float4*)(bb + c0);
        short4 o4;
        o4.x = f2bf((v0 - mu) * inv * gv.x + bv.x);
        o4.y = f2bf((v1 - mu) * inv * gv.y + bv.y);
        o4.z = f2bf((v2 - mu) * inv * gv.z + bv.z);
        o4.w = f2bf((v3 - mu) * inv * gv.w + bv.w);
        *(short4*)(out + (size_t)trow * HD + c0) = o4;
    }
}

// ---------------------------------------------------------------------------
// Final: gate = sigmoid(x@Wg_top + gs2@Wg_bot + bg); out = x + gate*(gs2@Wp+bp)
// Tile 64x64, grid (4,256)=1024, LDS 46KB -> 3 blocks/CU.
// ---------------------------------------------------------------------------
__global__ __launch_bounds__(256) void final_mfma(const short* __restrict__ xb,
                                                  const short* __restrict__ gs2b,
                                                  const short* __restrict__ WgT,
                                                  const float* __restrict__ bg,
                                                  const short* __restrict__ WpT,
                                                  const float* __restrict__ bp,
                                                  float* __restrict__ out)
{
    __shared__ __align__(16) short lX[64 * LDP];
    __shared__ __align__(16) short lG[64 * LDP];
    __shared__ __align__(16) short lB1[64 * LDP];
    __shared__ __align__(16) short lB2[64 * LDP];
    __shared__ __align__(16) short lB3[64 * LDP];
    int tid = threadIdx.x;
    int lane = tid & 63, wid = tid >> 6;
    int m0 = blockIdx.y * 64;
    int n0 = blockIdx.x * 64;
    int wrow = wid * 16;
    int lm = lane & 15, lk = (lane >> 4) * 8;
    f32x4 accg[4] = {}, accp[4] = {};
    for (int kt = 0; kt < 4; ++kt) {
        int k0 = kt * 64;
        __syncthreads();
        stage_tile(xb,   HD,  m0, k0, lX, 64);
        stage_tile(gs2b, HD,  m0, k0, lG, 64);
        stage_tile(WgT,  512, n0, k0, lB1, 64);
        stage_tile(WgT,  512, n0, k0 + 256, lB2, 64);
        stage_tile(WpT,  HD,  n0, k0, lB3, 64);
        __syncthreads();
#pragma unroll
        for (int kk2 = 0; kk2 < 64; kk2 += 32) {
            int ro = (wrow + lm) * LDP + kk2 + lk;
            bf16x8 ax = *(const bf16x8*)(lX + ro);
            bf16x8 ag = *(const bf16x8*)(lG + ro);
            bf16x8 b1[4], b2[4], b3[4];
#pragma unroll
            for (int j = 0; j < 4; ++j) {
                int rb = (j * 16 + lm) * LDP + kk2 + lk;
                b1[j] = *(const bf16x8*)(lB1 + rb);
                b2[j] = *(const bf16x8*)(lB2 + rb);
                b3[j] = *(const bf16x8*)(lB3 + rb);
            }
#pragma unroll
            for (int j = 0; j < 4; ++j) {
                accg[j] = __builtin_amdgcn_mfma_f32_16x16x32_bf16(ax, b1[j], accg[j], 0, 0, 0);
                accg[j] = __builtin_amdgcn_mfma_f32_16x16x32_bf16(ag, b2[j], accg[j], 0, 0, 0);
                accp[j] = __builtin_amdgcn_mfma_f32_16x16x32_bf16(ag, b3[j], accp[j], 0, 0, 0);
            }
        }
    }
    int rbase = (lane >> 4) * 4;
#pragma unroll
    for (int j = 0; j < 4; ++j)
#pragma unroll
        for (int r = 0; r < 4; ++r) {
            size_t m = (size_t)(m0 + wrow + rbase + r);
            int n = n0 + j * 16 + lm;
            float gate = 1.f / (1.f + __expf(-(accg[j][r] + bg[n])));
            float pv = accp[j][r] + bp[n];
            out[m * HD + n] = bf2f(xb[m * HD + n]) + gate * pv;
        }
}

// ---------------------------------------------------------------------------
extern "C" void kernel_launch(void* const* d_in, const int* in_sizes, int n_in,
                              void* d_out, int out_size, void* d_ws, size_t ws_size,
                              hipStream_t stream)
{
    const float* x     = (const float*)d_in[0];
    const float* Wc    = (const float*)d_in[1];
    const float* bc    = (const float*)d_in[2];
    const float* Wa    = (const float*)d_in[3];
    const float* a_src = (const float*)d_in[4];
    const float* a_tgt = (const float*)d_in[5];
    const float* ba    = (const float*)d_in[6];
    const float* ln_g  = (const float*)d_in[7];
    const float* ln_b  = (const float*)d_in[8];
    const float* Wg    = (const float*)d_in[9];
    const float* bg    = (const float*)d_in[10];
    const float* Wp    = (const float*)d_in[11];
    const float* bp    = (const float*)d_in[12];

    float* out = (float*)d_out;
    // d_out scratch (dead before final writes): h (8.4MB) + es/et
    short* hb  = (short*)d_out;
    char* dsec = (char*)d_out + (size_t)NR * HD * 2;
    float* es  = (float*)dsec;
    float* et  = es + (size_t)NR * NHEADS;

    char* w = (char*)d_ws;
    short* y   = (short*)w;   w += (size_t)NR * HD * 2;   // stencil(x) bf16
    short* zb  = (short*)w;   w += (size_t)NR * HD * 2;   // z, later gs2
    short* xb  = (short*)w;   w += (size_t)NR * HD * 2;   // bf16 x
    short* WcT = (short*)w;   w += 256 * 256 * 2;
    short* WaT = (short*)w;   w += 256 * 256 * 2;
    short* WpT = (short*)w;   w += 256 * 256 * 2;
    short* WgT = (short*)w;   w += 512 * 256 * 2;
    float* musum = (float*)w; w += (size_t)NR * 4;
    float* sqsum = (float*)w; w += (size_t)NR * 4;

    dim3 ggrid(HD / 64, NR / 64);    // (4, 256) = 1024 blocks

    // 0) merged: stencil+cast / weights^T / stats-zero
    prep_stencil<<<dim3(NR / SROWS, 6), 256, 0, stream>>>(
        x, Wc, Wa, Wg, Wp, xb, y, WcT, WaT, WgT, WpT, musum, sqsum);
    // 1) z = y@Wc + bc + xb; LN stats
    gemm1z<<<ggrid, 256, 0, stream>>>(y, WcT, xb, bc, zb, musum, sqsum);
    // 2) h = LN(z)@Wa (LN in staging) + es/et dots
    gemm_dots2<<<ggrid, 256, 0, stream>>>(zb, WaT, musum, sqsum, ln_g, ln_b,
                                          a_src, a_tgt, hb, es, et);
    // 3) gs2 = bf16(LN(attn_agg + ba + xb))  (LDS-tiled; z dead -> reuse zb)
    attn_ln<<<NR / SROWS, 256, 0, stream>>>(hb, es, et, xb, ba, ln_g, ln_b, zb);
    // 4) out = xb + sigmoid([xb,gs2]@Wg+bg) * (gs2@Wp+bp)
    final_mfma<<<ggrid, 256, 0, stream>>>(xb, zb, WgT, bg, WpT, bp, out);
}

// Round 10
// 69.868 us; speedup vs baseline: 1.8363x; 1.1645x over previous
//
#include <hip/hip_runtime.h>
#include <math.h>

#define HD 256
#define SEQ 4096
#define NR 16384
#define NHEADS 4
#define EPSV 1e-5f
#define LDP 72    // padded LDS row stride for GEMM K-tiles
#define ZLDP 264  // padded LDS row stride for the 256-wide LN(z) tile
#define SROWS 32  // stencil rows per block
#define SHALO 15  // 7 below + 8 above
#define SLDP 264  // stencil LDS row stride (elements)

typedef __attribute__((ext_vector_type(8))) short bf16x8;
typedef __attribute__((ext_vector_type(4))) float f32x4;

__device__ inline short f2bf(float f) {
    unsigned u = __float_as_uint(f);
    u += 0x7FFF + ((u >> 16) & 1);     // round-to-nearest-even
    return (short)(u >> 16);
}
__device__ inline float bf2f(short s) {
    return __uint_as_float(((unsigned)(unsigned short)s) << 16);
}

// Stage a [rows x 64] bf16 tile into padded LDS. Coalesced 16B chunks.
__device__ inline void stage_tile(const short* __restrict__ src, int src_stride,
                                  int row0, int k0, short* lds, int rows)
{
    int t = threadIdx.x;
    int nchunk = rows >> 5;
#pragma unroll
    for (int c = 0; c < 8; ++c) {
        if (c >= nchunk) break;
        int idx = c * 256 + t;
        int r = idx >> 3, kg = idx & 7;
        bf16x8 v = *(const bf16x8*)(src + (size_t)(row0 + r) * src_stride + k0 + kg * 8);
        *(bf16x8*)(lds + r * LDP + kg * 8) = v;
    }
}

// ---------------------------------------------------------------------------
// Merged prep + stencil. grid (512, 5):
//  task 0: stencil+cast: xb = bf16(x), y = 15-tap stencil(x)
//  tasks 1-4: weight transpose+cast (Wc/Wa/Wg/Wp)
// ---------------------------------------------------------------------------
__global__ __launch_bounds__(256) void prep_stencil(
    const float* __restrict__ x,
    const float* __restrict__ Wc, const float* __restrict__ Wa,
    const float* __restrict__ Wg, const float* __restrict__ Wp,
    short* __restrict__ xb, short* __restrict__ y,
    short* __restrict__ WcT, short* __restrict__ WaT,
    short* __restrict__ WgT, short* __restrict__ WpT)
{
    __shared__ __align__(16) char smem[(SROWS + SHALO) * SLDP * 2];
    int task = blockIdx.y;
    int bx = blockIdx.x;
    int t = threadIdx.x;

    if (task == 0) {                   // stencil + cast
        short* lH = (short*)smem;
        int t0 = bx * SROWS;
        int batch_base = t0 & ~(SEQ - 1);
        for (int i = t; i < (SROWS + SHALO) * 64; i += 256) {
            int r = i >> 6, c4 = (i & 63) * 4;
            int grow = t0 - 7 + r;
            short4 o4 = {0, 0, 0, 0};
            if (grow >= batch_base && grow < batch_base + SEQ) {
                float4 v = *(const float4*)(x + (size_t)grow * HD + c4);
                o4.x = f2bf(v.x); o4.y = f2bf(v.y); o4.z = f2bf(v.z); o4.w = f2bf(v.w);
            }
            *(short4*)(lH + r * SLDP + c4) = o4;
        }
        __syncthreads();
        for (int i = t; i < SROWS * 64; i += 256) {
            int r = i >> 6, c4 = (i & 63) * 4;
            *(short4*)(xb + (size_t)(t0 + r) * HD + c4) =
                *(const short4*)(lH + (r + 7) * SLDP + c4);
        }
        int wv = t >> 6, lane = t & 63;
        int c0 = lane * 4;
        for (int rr = wv; rr < SROWS; rr += 4) {
            float a0 = 0.f, a1 = 0.f, a2 = 0.f, a3 = 0.f;
#pragma unroll
            for (int i = 0; i < 15; ++i) {
                int d = (i < 7) ? (i - 7) : (i - 6);   // -7..-1, 1..8
                float wd = 1.f / (1.f + (float)((d < 0) ? -d : d));
                short4 s4 = *(const short4*)(lH + (rr + 7 + d) * SLDP + c0);
                a0 += wd * bf2f(s4.x); a1 += wd * bf2f(s4.y);
                a2 += wd * bf2f(s4.z); a3 += wd * bf2f(s4.w);
            }
            short4 o;
            o.x = f2bf(a0); o.y = f2bf(a1); o.z = f2bf(a2); o.w = f2bf(a3);
            *(short4*)(y + (size_t)(t0 + rr) * HD + c0) = o;
        }
        return;
    }
    // tasks 1-4: W^T via LDS tile (64x64)
    float (*lds)[65] = (float (*)[65])smem;
    const float* W; short* Wt; int K;
    if (task == 1)      { W = Wc; Wt = WcT; K = 256; }
    else if (task == 2) { W = Wa; Wt = WaT; K = 256; }
    else if (task == 3) { W = Wg; Wt = WgT; K = 512; }
    else                { W = Wp; Wt = WpT; K = 256; }
    int ntiles = (K >> 6) * 4;
    if (bx >= ntiles) return;
    int k0 = (bx >> 2) * 64, n0 = (bx & 3) * 64;
    int ty = t >> 6, tx = t & 63;
#pragma unroll
    for (int s = 0; s < 16; ++s) {
        int r = s * 4 + ty;
        lds[r][tx] = W[(size_t)(k0 + r) * 256 + n0 + tx];
    }
    __syncthreads();
#pragma unroll
    for (int s = 0; s < 16; ++s) {
        int rn = s * 4 + ty;
        Wt[(size_t)(n0 + rn) * K + k0 + tx] = f2bf(lds[tx][rn]);
    }
}

// ---------------------------------------------------------------------------
// Fused middle: block owns 32 FULL rows.
//  Phase 1: z = y@Wc + bc + xb (regs) -> row LN stats (local) -> LN(z) to LDS
//  Phase 2: h = LN(z) @ Wa (A from LDS) -> global; es/et dots (wave-local)
// Waves: 2(M) x 2(N-half of 128). No atomics, z never hits global.
// ---------------------------------------------------------------------------
__global__ __launch_bounds__(256) void gemm_fused(
    const short* __restrict__ y, const short* __restrict__ WcT,
    const short* __restrict__ xb, const float* __restrict__ bc,
    const short* __restrict__ WaT,
    const float* __restrict__ lng, const float* __restrict__ lnb,
    const float* __restrict__ a_src, const float* __restrict__ a_tgt,
    short* __restrict__ hb, float* __restrict__ es, float* __restrict__ et)
{
    __shared__ __align__(16) short lA[32 * LDP];      // 4.6 KB
    __shared__ __align__(16) short lB[256 * LDP];     // 36.9 KB
    __shared__ __align__(16) short lZ[32 * ZLDP];     // 16.9 KB
    __shared__ float red_s[2][32], red_q[2][32];
    int t = threadIdx.x;
    int lane = t & 63, wid = t >> 6;
    int wm = wid & 1, wn = wid >> 1;
    int m0 = blockIdx.x * 32;
    int lm = lane & 15, lk = (lane >> 4) * 8;
    int rbase = (lane >> 4) * 4;

    // ---- Phase 1: z = y@Wc ----
    f32x4 acc[8] = {};
    for (int kt = 0; kt < 4; ++kt) {
        __syncthreads();
        {   // stage y tile 32x64 (1 chunk/thread)
            int r = t >> 3, kg = t & 7;
            *(bf16x8*)(lA + r * LDP + kg * 8) =
                *(const bf16x8*)(y + (size_t)(m0 + r) * HD + kt * 64 + kg * 8);
        }
        stage_tile(WcT, HD, 0, kt * 64, lB, 256);
        __syncthreads();
#pragma unroll
        for (int kk2 = 0; kk2 < 64; kk2 += 32) {
            bf16x8 a = *(const bf16x8*)(lA + (wm * 16 + lm) * LDP + kk2 + lk);
#pragma unroll
            for (int j = 0; j < 8; ++j) {
                bf16x8 b = *(const bf16x8*)(lB + (wn * 128 + j * 16 + lm) * LDP + kk2 + lk);
                acc[j] = __builtin_amdgcn_mfma_f32_16x16x32_bf16(a, b, acc[j], 0, 0, 0);
            }
        }
    }
    // z + bias + residual, row stats
    float zv[8][4];
    float s4r[4] = {}, q4r[4] = {};
#pragma unroll
    for (int j = 0; j < 8; ++j)
#pragma unroll
        for (int r = 0; r < 4; ++r) {
            int n = wn * 128 + j * 16 + lm;
            int row = m0 + wm * 16 + rbase + r;
            float z = acc[j][r] + bc[n] + bf2f(xb[(size_t)row * HD + n]);
            zv[j][r] = z; s4r[r] += z; q4r[r] += z * z;
        }
#pragma unroll
    for (int r = 0; r < 4; ++r)
#pragma unroll
        for (int o = 1; o < 16; o <<= 1) {
            s4r[r] += __shfl_xor(s4r[r], o, 64);
            q4r[r] += __shfl_xor(q4r[r], o, 64);
        }
    if (lm == 0)
#pragma unroll
        for (int r = 0; r < 4; ++r) {
            red_s[wn][wm * 16 + rbase + r] = s4r[r];
            red_q[wn][wm * 16 + rbase + r] = q4r[r];
        }
    __syncthreads();
    float mu[4], inv[4];
#pragma unroll
    for (int r = 0; r < 4; ++r) {
        int rowl = wm * 16 + rbase + r;
        float S = red_s[0][rowl] + red_s[1][rowl];
        float Q = red_q[0][rowl] + red_q[1][rowl];
        mu[r] = S * (1.f / HD);
        inv[r] = rsqrtf(Q * (1.f / HD) - mu[r] * mu[r] + EPSV);
    }
    // LN(z) -> lZ
#pragma unroll
    for (int j = 0; j < 8; ++j)
#pragma unroll
        for (int r = 0; r < 4; ++r) {
            int n = wn * 128 + j * 16 + lm;
            int rowl = wm * 16 + rbase + r;
            lZ[rowl * ZLDP + n] = f2bf((zv[j][r] - mu[r]) * inv[r] * lng[n] + lnb[n]);
        }

    // ---- Phase 2: h = LN(z) @ Wa ----
    f32x4 acc2[8] = {};
    for (int kt = 0; kt < 4; ++kt) {
        __syncthreads();   // lZ complete (kt=0) / lB reads done (kt>0)
        stage_tile(WaT, HD, 0, kt * 64, lB, 256);
        __syncthreads();
#pragma unroll
        for (int kk2 = 0; kk2 < 64; kk2 += 32) {
            bf16x8 a = *(const bf16x8*)(lZ + (wm * 16 + lm) * ZLDP + kt * 64 + kk2 + lk);
#pragma unroll
            for (int j = 0; j < 8; ++j) {
                bf16x8 b = *(const bf16x8*)(lB + (wn * 128 + j * 16 + lm) * LDP + kk2 + lk);
                acc2[j] = __builtin_amdgcn_mfma_f32_16x16x32_bf16(a, b, acc2[j], 0, 0, 0);
            }
        }
    }
    // write h + wave-local es/et (head = wn*2 + (j>>2))
    float esA[4] = {}, etA[4] = {}, esB[4] = {}, etB[4] = {};
#pragma unroll
    for (int j = 0; j < 8; ++j) {
        int n = wn * 128 + j * 16 + lm;
        float as = a_src[n], at = a_tgt[n];
#pragma unroll
        for (int r = 0; r < 4; ++r) {
            int row = m0 + wm * 16 + rbase + r;
            hb[(size_t)row * HD + n] = f2bf(acc2[j][r]);
            if (j < 4) { esA[r] += acc2[j][r] * as; etA[r] += acc2[j][r] * at; }
            else       { esB[r] += acc2[j][r] * as; etB[r] += acc2[j][r] * at; }
        }
    }
#pragma unroll
    for (int r = 0; r < 4; ++r) {
#pragma unroll
        for (int o = 1; o < 16; o <<= 1) {
            esA[r] += __shfl_xor(esA[r], o, 64);
            etA[r] += __shfl_xor(etA[r], o, 64);
            esB[r] += __shfl_xor(esB[r], o, 64);
            etB[r] += __shfl_xor(etB[r], o, 64);
        }
        if (lm == 0) {
            int row = m0 + wm * 16 + rbase + r;
            es[row * NHEADS + wn * 2 + 0] = esA[r];
            et[row * NHEADS + wn * 2 + 0] = etA[r];
            es[row * NHEADS + wn * 2 + 1] = esB[r];
            et[row * NHEADS + wn * 2 + 1] = etB[r];
        }
    }
}

// ---------------------------------------------------------------------------
// Layer 1, LDS-tiled: block owns 32 rows; stages 47 rows of h into LDS once.
// Per row (wave): inline per-head softmax + 15-tap LDS aggregation + LN.
// ---------------------------------------------------------------------------
__global__ __launch_bounds__(256) void attn_ln(const short* __restrict__ hb,
                                               const float* __restrict__ es,
                                               const float* __restrict__ et,
                                               const short* __restrict__ xb,
                                               const float* __restrict__ ba,
                                               const float* __restrict__ g,
                                               const float* __restrict__ bb,
                                               short* __restrict__ out)
{
    __shared__ short lH[(SROWS + SHALO) * SLDP];
    int t0 = blockIdx.x * SROWS;
    int batch_base = t0 & ~(SEQ - 1);
    int t = threadIdx.x;
    for (int i = t; i < (SROWS + SHALO) * 64; i += 256) {
        int r = i >> 6, c4 = (i & 63) * 4;
        int grow = t0 - 7 + r;
        short4 v = {0, 0, 0, 0};
        if (grow >= batch_base && grow < batch_base + SEQ)
            v = *(const short4*)(hb + (size_t)grow * HD + c4);
        *(short4*)(lH + r * SLDP + c4) = v;
    }
    __syncthreads();

    int wv = t >> 6, lane = t & 63;
    int tap = lane >> 2, hh = lane & 3;
    int hd = lane >> 4;
    int c0 = lane * 4;
    for (int rr = wv; rr < SROWS; rr += 4) {
        int trow = t0 + rr;
        int p = trow & (SEQ - 1);
        float lg = -1e30f, wd = 0.f;
        bool okk = false;
        if (tap < 15) {
            int d = (tap < 7) ? (tap - 7) : (tap - 6);
            int qp = p + d;
            okk = (qp >= 0) && (qp < SEQ);
            if (okk) {
                float l = es[(trow + d) * NHEADS + hh] + et[trow * NHEADS + hh];
                lg = (l > 0.f) ? l : 0.2f * l;
            }
            wd = 1.f / (1.f + (float)((d < 0) ? -d : d));
        }
        float m = lg;
#pragma unroll
        for (int o = 4; o < 64; o <<= 1) m = fmaxf(m, __shfl_xor(m, o, 64));
        float un = okk ? __expf(lg - m) * wd : 0.f;
        float den = un;
#pragma unroll
        for (int o = 4; o < 64; o <<= 1) den += __shfl_xor(den, o, 64);
        float alpha_l = un / (den + 1e-9f);

        float al[15];
#pragma unroll
        for (int i = 0; i < 15; ++i) al[i] = __shfl(alpha_l, i * 4 + hd, 64);

        float a0 = 0.f, a1 = 0.f, a2 = 0.f, a3 = 0.f;
#pragma unroll
        for (int i = 0; i < 15; ++i) {
            int d = (i < 7) ? (i - 7) : (i - 6);
            short4 s4 = *(const short4*)(lH + (rr + 7 + d) * SLDP + c0);
            a0 += al[i] * bf2f(s4.x); a1 += al[i] * bf2f(s4.y);
            a2 += al[i] * bf2f(s4.z); a3 += al[i] * bf2f(s4.w);
        }
        short4 xv4 = *(const short4*)(xb + (size_t)trow * HD + c0);
        float4 bav = *(const float4*)(ba + c0);
        float v0 = a0 + bav.x + bf2f(xv4.x), v1 = a1 + bav.y + bf2f(xv4.y);
        float v2 = a2 + bav.z + bf2f(xv4.z), v3 = a3 + bav.w + bf2f(xv4.w);
        float s = v0 + v1 + v2 + v3;
        float q = v0 * v0 + v1 * v1 + v2 * v2 + v3 * v3;
#pragma unroll
        for (int o = 1; o < 64; o <<= 1) { s += __shfl_xor(s, o, 64); q += __shfl_xor(q, o, 64); }
        float mu = s * (1.f / HD);
        float var = q * (1.f / HD) - mu * mu;
        float inv = rsqrtf(var + EPSV);
        float4 gv = *(const float4*)(g + c0);
        float4 bv = *(const float4*)(bb + c0);
        short4 o4;
        o4.x = f2bf((v0 - mu) * inv * gv.x + bv.x);
        o4.y = f2bf((v1 - mu) * inv * gv.y + bv.y);
        o4.z = f2bf((v2 - mu) * inv * gv.z + bv.z);
        o4.w = f2bf((v3 - mu) * inv * gv.w + bv.w);
        *(short4*)(out + (size_t)trow * HD + c0) = o4;
    }
}

// ---------------------------------------------------------------------------
// Final: gate = sigmoid(x@Wg_top + gs2@Wg_bot + bg); out = x + gate*(gs2@Wp+bp)
// Tile 64x64, grid (4,256)=1024.
// ---------------------------------------------------------------------------
__global__ __launch_bounds__(256) void final_mfma(const short* __restrict__ xb,
                                                  const short* __restrict__ gs2b,
                                                  const short* __restrict__ WgT,
                                                  const float* __restrict__ bg,
                                                  const short* __restrict__ WpT,
                                                  const float* __restrict__ bp,
                                                  float* __restrict__ out)
{
    __shared__ __align__(16) short lX[64 * LDP];
    __shared__ __align__(16) short lG[64 * LDP];
    __shared__ __align__(16) short lB1[64 * LDP];
    __shared__ __align__(16) short lB2[64 * LDP];
    __shared__ __align__(16) short lB3[64 * LDP];
    int tid = threadIdx.x;
    int lane = tid & 63, wid = tid >> 6;
    int m0 = blockIdx.y * 64;
    int n0 = blockIdx.x * 64;
    int wrow = wid * 16;
    int lm = lane & 15, lk = (lane >> 4) * 8;
    f32x4 accg[4] = {}, accp[4] = {};
    for (int kt = 0; kt < 4; ++kt) {
        int k0 = kt * 64;
        __syncthreads();
        stage_tile(xb,   HD,  m0, k0, lX, 64);
        stage_tile(gs2b, HD,  m0, k0, lG, 64);
        stage_tile(WgT,  512, n0, k0, lB1, 64);
        stage_tile(WgT,  512, n0, k0 + 256, lB2, 64);
        stage_tile(WpT,  HD,  n0, k0, lB3, 64);
        __syncthreads();
#pragma unroll
        for (int kk2 = 0; kk2 < 64; kk2 += 32) {
            int ro = (wrow + lm) * LDP + kk2 + lk;
            bf16x8 ax = *(const bf16x8*)(lX + ro);
            bf16x8 ag = *(const bf16x8*)(lG + ro);
            bf16x8 b1[4], b2[4], b3[4];
#pragma unroll
            for (int j = 0; j < 4; ++j) {
                int rb = (j * 16 + lm) * LDP + kk2 + lk;
                b1[j] = *(const bf16x8*)(lB1 + rb);
                b2[j] = *(const bf16x8*)(lB2 + rb);
                b3[j] = *(const bf16x8*)(lB3 + rb);
            }
#pragma unroll
            for (int j = 0; j < 4; ++j) {
                accg[j] = __builtin_amdgcn_mfma_f32_16x16x32_bf16(ax, b1[j], accg[j], 0, 0, 0);
                accg[j] = __builtin_amdgcn_mfma_f32_16x16x32_bf16(ag, b2[j], accg[j], 0, 0, 0);
                accp[j] = __builtin_amdgcn_mfma_f32_16x16x32_bf16(ag, b3[j], accp[j], 0, 0, 0);
            }
        }
    }
    int rbase = (lane >> 4) * 4;
#pragma unroll
    for (int j = 0; j < 4; ++j)
#pragma unroll
        for (int r = 0; r < 4; ++r) {
            size_t m = (size_t)(m0 + wrow + rbase + r);
            int n = n0 + j * 16 + lm;
            float gate = 1.f / (1.f + __expf(-(accg[j][r] + bg[n])));
            float pv = accp[j][r] + bp[n];
            out[m * HD + n] = bf2f(xb[m * HD + n]) + gate * pv;
        }
}

// ---------------------------------------------------------------------------
extern "C" void kernel_launch(void* const* d_in, const int* in_sizes, int n_in,
                              void* d_out, int out_size, void* d_ws, size_t ws_size,
                              hipStream_t stream)
{
    const float* x     = (const float*)d_in[0];
    const float* Wc    = (const float*)d_in[1];
    const float* bc    = (const float*)d_in[2];
    const float* Wa    = (const float*)d_in[3];
    const float* a_src = (const float*)d_in[4];
    const float* a_tgt = (const float*)d_in[5];
    const float* ba    = (const float*)d_in[6];
    const float* ln_g  = (const float*)d_in[7];
    const float* ln_b  = (const float*)d_in[8];
    const float* Wg    = (const float*)d_in[9];
    const float* bg    = (const float*)d_in[10];
    const float* Wp    = (const float*)d_in[11];
    const float* bp    = (const float*)d_in[12];

    float* out = (float*)d_out;
    // d_out scratch (dead before final writes): h (8.4MB) + es/et
    short* hb  = (short*)d_out;
    char* dsec = (char*)d_out + (size_t)NR * HD * 2;
    float* es  = (float*)dsec;
    float* et  = es + (size_t)NR * NHEADS;

    char* w = (char*)d_ws;
    short* y   = (short*)w;   w += (size_t)NR * HD * 2;   // stencil(x) bf16
    short* gsb = (short*)w;   w += (size_t)NR * HD * 2;   // gs2
    short* xb  = (short*)w;   w += (size_t)NR * HD * 2;   // bf16 x
    short* WcT = (short*)w;   w += 256 * 256 * 2;
    short* WaT = (short*)w;   w += 256 * 256 * 2;
    short* WpT = (short*)w;   w += 256 * 256 * 2;
    short* WgT = (short*)w;   w += 512 * 256 * 2;

    dim3 ggrid(HD / 64, NR / 64);    // (4, 256) = 1024 blocks

    // 0) merged: stencil+cast / weights^T
    prep_stencil<<<dim3(NR / SROWS, 5), 256, 0, stream>>>(
        x, Wc, Wa, Wg, Wp, xb, y, WcT, WaT, WgT, WpT);
    // 1) fused: z=y@Wc+bc+xb -> LN -> h=LN(z)@Wa -> es/et   (z stays in LDS)
    gemm_fused<<<NR / 32, 256, 0, stream>>>(y, WcT, xb, bc, WaT, ln_g, ln_b,
                                            a_src, a_tgt, hb, es, et);
    // 2) gs2 = bf16(LN(attn_agg + ba + xb))  (LDS-tiled)
    attn_ln<<<NR / SROWS, 256, 0, stream>>>(hb, es, et, xb, ba, ln_g, ln_b, gsb);
    // 3) out = xb + sigmoid([xb,gs2]@Wg+bg) * (gs2@Wp+bp)
    final_mfma<<<ggrid, 256, 0, stream>>>(xb, gsb, WgT, bg, WpT, bp, out);
}

// Round 11
// 66.523 us; speedup vs baseline: 1.9286x; 1.0503x over previous
//
#include <hip/hip_runtime.h>
#include <math.h>

#define HD 256
#define SEQ 4096
#define NR 16384
#define NHEADS 4
#define EPSV 1e-5f
#define LDP 72    // padded LDS row stride for GEMM K-tiles
#define ZLDP 264  // padded LDS row stride for 256-wide row tiles
#define SROWS 32  // stencil/attn rows per block
#define SHALO 15  // 7 below + 8 above
#define SLDP 264  // halo-tile LDS row stride

typedef __attribute__((ext_vector_type(8))) short bf16x8;
typedef __attribute__((ext_vector_type(4))) float f32x4;

__device__ inline short f2bf(float f) {
    unsigned u = __float_as_uint(f);
    u += 0x7FFF + ((u >> 16) & 1);     // round-to-nearest-even
    return (short)(u >> 16);
}
__device__ inline float bf2f(short s) {
    return __uint_as_float(((unsigned)(unsigned short)s) << 16);
}

// Stage a [rows x 64] bf16 tile into padded LDS. Coalesced 16B chunks.
__device__ inline void stage_tile(const short* __restrict__ src, int src_stride,
                                  int row0, int k0, short* lds, int rows)
{
    int t = threadIdx.x;
    int nchunk = rows >> 5;
#pragma unroll
    for (int c = 0; c < 8; ++c) {
        if (c >= nchunk) break;
        int idx = c * 256 + t;
        int r = idx >> 3, kg = idx & 7;
        bf16x8 v = *(const bf16x8*)(src + (size_t)(row0 + r) * src_stride + k0 + kg * 8);
        *(bf16x8*)(lds + r * LDP + kg * 8) = v;
    }
}

// ---------------------------------------------------------------------------
// Merged prep + stencil. grid (512, 5):
//  task 0: stencil+cast: xb = bf16(x), y = 15-tap stencil(x)
//  tasks 1-4: weight transpose+cast (Wc/Wa/Wg/Wp)
// ---------------------------------------------------------------------------
__global__ __launch_bounds__(256) void prep_stencil(
    const float* __restrict__ x,
    const float* __restrict__ Wc, const float* __restrict__ Wa,
    const float* __restrict__ Wg, const float* __restrict__ Wp,
    short* __restrict__ xb, short* __restrict__ y,
    short* __restrict__ WcT, short* __restrict__ WaT,
    short* __restrict__ WgT, short* __restrict__ WpT)
{
    __shared__ __align__(16) char smem[(SROWS + SHALO) * SLDP * 2];
    int task = blockIdx.y;
    int bx = blockIdx.x;
    int t = threadIdx.x;

    if (task == 0) {                   // stencil + cast
        short* lH = (short*)smem;
        int t0 = bx * SROWS;
        int batch_base = t0 & ~(SEQ - 1);
        for (int i = t; i < (SROWS + SHALO) * 64; i += 256) {
            int r = i >> 6, c4 = (i & 63) * 4;
            int grow = t0 - 7 + r;
            short4 o4 = {0, 0, 0, 0};
            if (grow >= batch_base && grow < batch_base + SEQ) {
                float4 v = *(const float4*)(x + (size_t)grow * HD + c4);
                o4.x = f2bf(v.x); o4.y = f2bf(v.y); o4.z = f2bf(v.z); o4.w = f2bf(v.w);
            }
            *(short4*)(lH + r * SLDP + c4) = o4;
        }
        __syncthreads();
        for (int i = t; i < SROWS * 64; i += 256) {
            int r = i >> 6, c4 = (i & 63) * 4;
            *(short4*)(xb + (size_t)(t0 + r) * HD + c4) =
                *(const short4*)(lH + (r + 7) * SLDP + c4);
        }
        int wv = t >> 6, lane = t & 63;
        int c0 = lane * 4;
        for (int rr = wv; rr < SROWS; rr += 4) {
            float a0 = 0.f, a1 = 0.f, a2 = 0.f, a3 = 0.f;
#pragma unroll
            for (int i = 0; i < 15; ++i) {
                int d = (i < 7) ? (i - 7) : (i - 6);   // -7..-1, 1..8
                float wd = 1.f / (1.f + (float)((d < 0) ? -d : d));
                short4 s4 = *(const short4*)(lH + (rr + 7 + d) * SLDP + c0);
                a0 += wd * bf2f(s4.x); a1 += wd * bf2f(s4.y);
                a2 += wd * bf2f(s4.z); a3 += wd * bf2f(s4.w);
            }
            short4 o;
            o.x = f2bf(a0); o.y = f2bf(a1); o.z = f2bf(a2); o.w = f2bf(a3);
            *(short4*)(y + (size_t)(t0 + rr) * HD + c0) = o;
        }
        return;
    }
    // tasks 1-4: W^T via LDS tile (64x64)
    float (*lds)[65] = (float (*)[65])smem;
    const float* W; short* Wt; int K;
    if (task == 1)      { W = Wc; Wt = WcT; K = 256; }
    else if (task == 2) { W = Wa; Wt = WaT; K = 256; }
    else if (task == 3) { W = Wg; Wt = WgT; K = 512; }
    else                { W = Wp; Wt = WpT; K = 256; }
    int ntiles = (K >> 6) * 4;
    if (bx >= ntiles) return;
    int k0 = (bx >> 2) * 64, n0 = (bx & 3) * 64;
    int ty = t >> 6, tx = t & 63;
#pragma unroll
    for (int s = 0; s < 16; ++s) {
        int r = s * 4 + ty;
        lds[r][tx] = W[(size_t)(k0 + r) * 256 + n0 + tx];
    }
    __syncthreads();
#pragma unroll
    for (int s = 0; s < 16; ++s) {
        int rn = s * 4 + ty;
        Wt[(size_t)(n0 + rn) * K + k0 + tx] = f2bf(lds[tx][rn]);
    }
}

// ---------------------------------------------------------------------------
// Fused middle: block owns 32 FULL rows.
//  Phase 1: z = y@Wc + bc + xb (regs) -> row LN stats (local) -> LN(z) to LDS
//  Phase 2: h = LN(z) @ Wa (A from LDS) -> global; es/et dots (wave-local)
// ---------------------------------------------------------------------------
__global__ __launch_bounds__(256) void gemm_fused(
    const short* __restrict__ y, const short* __restrict__ WcT,
    const short* __restrict__ xb, const float* __restrict__ bc,
    const short* __restrict__ WaT,
    const float* __restrict__ lng, const float* __restrict__ lnb,
    const float* __restrict__ a_src, const float* __restrict__ a_tgt,
    short* __restrict__ hb, float* __restrict__ es, float* __restrict__ et)
{
    __shared__ __align__(16) short lA[32 * LDP];
    __shared__ __align__(16) short lB[256 * LDP];
    __shared__ __align__(16) short lZ[32 * ZLDP];
    __shared__ float red_s[2][32], red_q[2][32];
    int t = threadIdx.x;
    int lane = t & 63, wid = t >> 6;
    int wm = wid & 1, wn = wid >> 1;
    int m0 = blockIdx.x * 32;
    int lm = lane & 15, lk = (lane >> 4) * 8;
    int rbase = (lane >> 4) * 4;

    // ---- Phase 1: z = y@Wc ----
    f32x4 acc[8] = {};
    for (int kt = 0; kt < 4; ++kt) {
        __syncthreads();
        {   // stage y tile 32x64
            int r = t >> 3, kg = t & 7;
            *(bf16x8*)(lA + r * LDP + kg * 8) =
                *(const bf16x8*)(y + (size_t)(m0 + r) * HD + kt * 64 + kg * 8);
        }
        stage_tile(WcT, HD, 0, kt * 64, lB, 256);
        __syncthreads();
#pragma unroll
        for (int kk2 = 0; kk2 < 64; kk2 += 32) {
            bf16x8 a = *(const bf16x8*)(lA + (wm * 16 + lm) * LDP + kk2 + lk);
#pragma unroll
            for (int j = 0; j < 8; ++j) {
                bf16x8 b = *(const bf16x8*)(lB + (wn * 128 + j * 16 + lm) * LDP + kk2 + lk);
                acc[j] = __builtin_amdgcn_mfma_f32_16x16x32_bf16(a, b, acc[j], 0, 0, 0);
            }
        }
    }
    float zv[8][4];
    float s4r[4] = {}, q4r[4] = {};
#pragma unroll
    for (int j = 0; j < 8; ++j)
#pragma unroll
        for (int r = 0; r < 4; ++r) {
            int n = wn * 128 + j * 16 + lm;
            int row = m0 + wm * 16 + rbase + r;
            float z = acc[j][r] + bc[n] + bf2f(xb[(size_t)row * HD + n]);
            zv[j][r] = z; s4r[r] += z; q4r[r] += z * z;
        }
#pragma unroll
    for (int r = 0; r < 4; ++r)
#pragma unroll
        for (int o = 1; o < 16; o <<= 1) {
            s4r[r] += __shfl_xor(s4r[r], o, 64);
            q4r[r] += __shfl_xor(q4r[r], o, 64);
        }
    if (lm == 0)
#pragma unroll
        for (int r = 0; r < 4; ++r) {
            red_s[wn][wm * 16 + rbase + r] = s4r[r];
            red_q[wn][wm * 16 + rbase + r] = q4r[r];
        }
    __syncthreads();
    float mu[4], inv[4];
#pragma unroll
    for (int r = 0; r < 4; ++r) {
        int rowl = wm * 16 + rbase + r;
        float S = red_s[0][rowl] + red_s[1][rowl];
        float Q = red_q[0][rowl] + red_q[1][rowl];
        mu[r] = S * (1.f / HD);
        inv[r] = rsqrtf(Q * (1.f / HD) - mu[r] * mu[r] + EPSV);
    }
#pragma unroll
    for (int j = 0; j < 8; ++j)
#pragma unroll
        for (int r = 0; r < 4; ++r) {
            int n = wn * 128 + j * 16 + lm;
            int rowl = wm * 16 + rbase + r;
            lZ[rowl * ZLDP + n] = f2bf((zv[j][r] - mu[r]) * inv[r] * lng[n] + lnb[n]);
        }

    // ---- Phase 2: h = LN(z) @ Wa ----
    f32x4 acc2[8] = {};
    for (int kt = 0; kt < 4; ++kt) {
        __syncthreads();
        stage_tile(WaT, HD, 0, kt * 64, lB, 256);
        __syncthreads();
#pragma unroll
        for (int kk2 = 0; kk2 < 64; kk2 += 32) {
            bf16x8 a = *(const bf16x8*)(lZ + (wm * 16 + lm) * ZLDP + kt * 64 + kk2 + lk);
#pragma unroll
            for (int j = 0; j < 8; ++j) {
                bf16x8 b = *(const bf16x8*)(lB + (wn * 128 + j * 16 + lm) * LDP + kk2 + lk);
                acc2[j] = __builtin_amdgcn_mfma_f32_16x16x32_bf16(a, b, acc2[j], 0, 0, 0);
            }
        }
    }
    float esA[4] = {}, etA[4] = {}, esB[4] = {}, etB[4] = {};
#pragma unroll
    for (int j = 0; j < 8; ++j) {
        int n = wn * 128 + j * 16 + lm;
        float as = a_src[n], at = a_tgt[n];
#pragma unroll
        for (int r = 0; r < 4; ++r) {
            int row = m0 + wm * 16 + rbase + r;
            hb[(size_t)row * HD + n] = f2bf(acc2[j][r]);
            if (j < 4) { esA[r] += acc2[j][r] * as; etA[r] += acc2[j][r] * at; }
            else       { esB[r] += acc2[j][r] * as; etB[r] += acc2[j][r] * at; }
        }
    }
#pragma unroll
    for (int r = 0; r < 4; ++r) {
#pragma unroll
        for (int o = 1; o < 16; o <<= 1) {
            esA[r] += __shfl_xor(esA[r], o, 64);
            etA[r] += __shfl_xor(etA[r], o, 64);
            esB[r] += __shfl_xor(esB[r], o, 64);
            etB[r] += __shfl_xor(etB[r], o, 64);
        }
        if (lm == 0) {
            int row = m0 + wm * 16 + rbase + r;
            es[row * NHEADS + wn * 2 + 0] = esA[r];
            et[row * NHEADS + wn * 2 + 0] = etA[r];
            es[row * NHEADS + wn * 2 + 1] = esB[r];
            et[row * NHEADS + wn * 2 + 1] = etB[r];
        }
    }
}

// ---------------------------------------------------------------------------
// Fused tail: block owns 32 rows.
//  Phase A: attn + LN -> gs2 in LDS (h halo staged; xb staged; never global)
//  Phase B: gate = sigmoid(xb@Wg_top + gs2@Wg_bot + bg)  [2 staged passes]
//  Phase C: p = gs2@Wp + bp; out = xb + gate * p
// LDS: region0 = lH(24.8K) then lB(36.9K); lZ(16.9K); lX(16.9K) = 70.7KB.
// ---------------------------------------------------------------------------
#define AF_LZ_OFF (256 * LDP * 2)
#define AF_LX_OFF (256 * LDP * 2 + 32 * ZLDP * 2)

__global__ __launch_bounds__(256) void attn_final(
    const short* __restrict__ hb, const float* __restrict__ es,
    const float* __restrict__ et, const short* __restrict__ xb,
    const float* __restrict__ ba, const float* __restrict__ lng,
    const float* __restrict__ lnb,
    const short* __restrict__ WgT, const float* __restrict__ bg,
    const short* __restrict__ WpT, const float* __restrict__ bp,
    float* __restrict__ out)
{
    __shared__ __align__(16) char smem[256 * LDP * 2 + 2 * 32 * ZLDP * 2];
    short* lH = (short*)smem;                 // 47 x SLDP during attn
    short* lB = (short*)smem;                 // 256 x LDP during GEMMs
    short* lZ = (short*)(smem + AF_LZ_OFF);   // gs2, 32 x ZLDP
    short* lX = (short*)(smem + AF_LX_OFF);   // xb,  32 x ZLDP

    int t = threadIdx.x;
    int t0 = blockIdx.x * SROWS;
    int batch_base = t0 & ~(SEQ - 1);

    // stage h halo tile + xb own rows
    for (int i = t; i < (SROWS + SHALO) * 64; i += 256) {
        int r = i >> 6, c4 = (i & 63) * 4;
        int grow = t0 - 7 + r;
        short4 v = {0, 0, 0, 0};
        if (grow >= batch_base && grow < batch_base + SEQ)
            v = *(const short4*)(hb + (size_t)grow * HD + c4);
        *(short4*)(lH + r * SLDP + c4) = v;
    }
    for (int i = t; i < SROWS * 64; i += 256) {
        int r = i >> 6, c4 = (i & 63) * 4;
        *(short4*)(lX + r * ZLDP + c4) = *(const short4*)(xb + (size_t)(t0 + r) * HD + c4);
    }
    __syncthreads();

    // ---- Phase A: attn + LN -> lZ ----
    int wv = t >> 6, lane = t & 63;
    int tap = lane >> 2, hh = lane & 3;
    int hd = lane >> 4;
    int c0 = lane * 4;
    for (int rr = wv; rr < SROWS; rr += 4) {
        int trow = t0 + rr;
        int p = trow & (SEQ - 1);
        float lg = -1e30f, wd = 0.f;
        bool okk = false;
        if (tap < 15) {
            int d = (tap < 7) ? (tap - 7) : (tap - 6);
            int qp = p + d;
            okk = (qp >= 0) && (qp < SEQ);
            if (okk) {
                float l = es[(trow + d) * NHEADS + hh] + et[trow * NHEADS + hh];
                lg = (l > 0.f) ? l : 0.2f * l;
            }
            wd = 1.f / (1.f + (float)((d < 0) ? -d : d));
        }
        float m = lg;
#pragma unroll
        for (int o = 4; o < 64; o <<= 1) m = fmaxf(m, __shfl_xor(m, o, 64));
        float un = okk ? __expf(lg - m) * wd : 0.f;
        float den = un;
#pragma unroll
        for (int o = 4; o < 64; o <<= 1) den += __shfl_xor(den, o, 64);
        float alpha_l = un / (den + 1e-9f);

        float al[15];
#pragma unroll
        for (int i = 0; i < 15; ++i) al[i] = __shfl(alpha_l, i * 4 + hd, 64);

        float a0 = 0.f, a1 = 0.f, a2 = 0.f, a3 = 0.f;
#pragma unroll
        for (int i = 0; i < 15; ++i) {
            int d = (i < 7) ? (i - 7) : (i - 6);
            short4 s4 = *(const short4*)(lH + (rr + 7 + d) * SLDP + c0);
            a0 += al[i] * bf2f(s4.x); a1 += al[i] * bf2f(s4.y);
            a2 += al[i] * bf2f(s4.z); a3 += al[i] * bf2f(s4.w);
        }
        short4 xv4 = *(const short4*)(lX + rr * ZLDP + c0);
        float4 bav = *(const float4*)(ba + c0);
        float v0 = a0 + bav.x + bf2f(xv4.x), v1 = a1 + bav.y + bf2f(xv4.y);
        float v2 = a2 + bav.z + bf2f(xv4.z), v3 = a3 + bav.w + bf2f(xv4.w);
        float s = v0 + v1 + v2 + v3;
        float q = v0 * v0 + v1 * v1 + v2 * v2 + v3 * v3;
#pragma unroll
        for (int o = 1; o < 64; o <<= 1) { s += __shfl_xor(s, o, 64); q += __shfl_xor(q, o, 64); }
        float mu = s * (1.f / HD);
        float var = q * (1.f / HD) - mu * mu;
        float inv = rsqrtf(var + EPSV);
        float4 gv = *(const float4*)(lng + c0);
        float4 bv = *(const float4*)(lnb + c0);
        short4 o4;
        o4.x = f2bf((v0 - mu) * inv * gv.x + bv.x);
        o4.y = f2bf((v1 - mu) * inv * gv.y + bv.y);
        o4.z = f2bf((v2 - mu) * inv * gv.z + bv.z);
        o4.w = f2bf((v3 - mu) * inv * gv.w + bv.w);
        *(short4*)(lZ + rr * ZLDP + c0) = o4;
    }

    // ---- Phases B/C: three staged GEMM passes ----
    int wid = t >> 6;
    int wm = wid & 1, wn = wid >> 1;
    int lm = lane & 15, lk = (lane >> 4) * 8;
    int rbase = (lane >> 4) * 4;
    f32x4 accg[8] = {}, accp[8] = {};
    // pass 1: accg += xb @ Wg_top
    for (int kt = 0; kt < 4; ++kt) {
        __syncthreads();
        stage_tile(WgT, 512, 0, kt * 64, lB, 256);
        __syncthreads();
#pragma unroll
        for (int kk2 = 0; kk2 < 64; kk2 += 32) {
            bf16x8 a = *(const bf16x8*)(lX + (wm * 16 + lm) * ZLDP + kt * 64 + kk2 + lk);
#pragma unroll
            for (int j = 0; j < 8; ++j) {
                bf16x8 b = *(const bf16x8*)(lB + (wn * 128 + j * 16 + lm) * LDP + kk2 + lk);
                accg[j] = __builtin_amdgcn_mfma_f32_16x16x32_bf16(a, b, accg[j], 0, 0, 0);
            }
        }
    }
    // pass 2: accg += gs2 @ Wg_bot
    for (int kt = 0; kt < 4; ++kt) {
        __syncthreads();
        stage_tile(WgT, 512, 0, 256 + kt * 64, lB, 256);
        __syncthreads();
#pragma unroll
        for (int kk2 = 0; kk2 < 64; kk2 += 32) {
            bf16x8 a = *(const bf16x8*)(lZ + (wm * 16 + lm) * ZLDP + kt * 64 + kk2 + lk);
#pragma unroll
            for (int j = 0; j < 8; ++j) {
                bf16x8 b = *(const bf16x8*)(lB + (wn * 128 + j * 16 + lm) * LDP + kk2 + lk);
                accg[j] = __builtin_amdgcn_mfma_f32_16x16x32_bf16(a, b, accg[j], 0, 0, 0);
            }
        }
    }
    // pass 3: accp = gs2 @ Wp
    for (int kt = 0; kt < 4; ++kt) {
        __syncthreads();
        stage_tile(WpT, HD, 0, kt * 64, lB, 256);
        __syncthreads();
#pragma unroll
        for (int kk2 = 0; kk2 < 64; kk2 += 32) {
            bf16x8 a = *(const bf16x8*)(lZ + (wm * 16 + lm) * ZLDP + kt * 64 + kk2 + lk);
#pragma unroll
            for (int j = 0; j < 8; ++j) {
                bf16x8 b = *(const bf16x8*)(lB + (wn * 128 + j * 16 + lm) * LDP + kk2 + lk);
                accp[j] = __builtin_amdgcn_mfma_f32_16x16x32_bf16(a, b, accp[j], 0, 0, 0);
            }
        }
    }
    // epilogue
#pragma unroll
    for (int j = 0; j < 8; ++j)
#pragma unroll
        for (int r = 0; r < 4; ++r) {
            int n = wn * 128 + j * 16 + lm;
            int rowl = wm * 16 + rbase + r;
            size_t m = (size_t)(t0 + rowl);
            float gate = 1.f / (1.f + __expf(-(accg[j][r] + bg[n])));
            float pv = accp[j][r] + bp[n];
            out[m * HD + n] = bf2f(lX[rowl * ZLDP + n]) + gate * pv;
        }
}

// ---------------------------------------------------------------------------
extern "C" void kernel_launch(void* const* d_in, const int* in_sizes, int n_in,
                              void* d_out, int out_size, void* d_ws, size_t ws_size,
                              hipStream_t stream)
{
    const float* x     = (const float*)d_in[0];
    const float* Wc    = (const float*)d_in[1];
    const float* bc    = (const float*)d_in[2];
    const float* Wa    = (const float*)d_in[3];
    const float* a_src = (const float*)d_in[4];
    const float* a_tgt = (const float*)d_in[5];
    const float* ba    = (const float*)d_in[6];
    const float* ln_g  = (const float*)d_in[7];
    const float* ln_b  = (const float*)d_in[8];
    const float* Wg    = (const float*)d_in[9];
    const float* bg    = (const float*)d_in[10];
    const float* Wp    = (const float*)d_in[11];
    const float* bp    = (const float*)d_in[12];

    float* out = (float*)d_out;      // written ONLY by attn_final (h now in ws)

    char* w = (char*)d_ws;
    short* y   = (short*)w;   w += (size_t)NR * HD * 2;   // stencil(x) bf16
    short* xb  = (short*)w;   w += (size_t)NR * HD * 2;   // bf16 x
    short* hb  = (short*)w;   w += (size_t)NR * HD * 2;   // h bf16
    float* es  = (float*)w;   w += (size_t)NR * NHEADS * 4;
    float* et  = (float*)w;   w += (size_t)NR * NHEADS * 4;
    short* WcT = (short*)w;   w += 256 * 256 * 2;
    short* WaT = (short*)w;   w += 256 * 256 * 2;
    short* WpT = (short*)w;   w += 256 * 256 * 2;
    short* WgT = (short*)w;   w += 512 * 256 * 2;

    // 0) merged: stencil+cast / weights^T
    prep_stencil<<<dim3(NR / SROWS, 5), 256, 0, stream>>>(
        x, Wc, Wa, Wg, Wp, xb, y, WcT, WaT, WgT, WpT);
    // 1) fused: z=y@Wc+bc+xb -> LN -> h=LN(z)@Wa -> es/et   (z stays in LDS)
    gemm_fused<<<NR / 32, 256, 0, stream>>>(y, WcT, xb, bc, WaT, ln_g, ln_b,
                                            a_src, a_tgt, hb, es, et);
    // 2) fused: gs2 = LN(attn(h)+ba+xb) in LDS -> out = xb + gate*(gs2@Wp+bp)
    attn_final<<<NR / SROWS, 256, 0, stream>>>(hb, es, et, xb, ba, ln_g, ln_b,
                                               WgT, bg, WpT, bp, out);
}